// Round 8
// baseline (493.629 us; speedup 1.0000x reference)
//
#include <hip/hip_runtime.h>
#include <cstdint>
#include <cstddef>

// ---------------------------------------------------------------------------
// GCN forward:  softmax( (A_hat relu(A_hat (X W1 + b1) W2)) Wl + bl )
// conv1 reordered: aggregate features (F=512) first, GEMM1 epilogue adds
// rowsum*b1. conv2: project (8192->4096) then aggregate.
// GEMM (R8): 256x256 tile, BK=64, 8 waves (2M x 4N), 2-buffer LDS (128KB),
// ONE-PHASE-LOOKAHEAD quadrant pipeline (m201 mechanism): each phase's
// ds_reads feed the NEXT phase's MFMA, so the compiler's auto waitcnt before
// each MFMA cluster is a counted lgkm (already satisfied) and LDS service
// overlaps the MFMA cluster. 4 phases/K-tile (Q0..Q3, 16 MFMA each),
// 2 raw s_barriers/phase, counted vmcnt(6) once per tile (never drains in
// steady state). T2 XOR swizzle both sides, T5 setprio, XCD-chunk swizzle.
// agg2: 512-col stripes pinned to XCDs via bid%8 -> gather from L2.
// ---------------------------------------------------------------------------

using bf8   = __attribute__((ext_vector_type(8))) short;   // 8 bf16 (4 VGPR)
using s4    = __attribute__((ext_vector_type(4))) short;
using f32x4 = __attribute__((ext_vector_type(4))) float;

static __device__ __forceinline__ unsigned short f2bf(float f) {
    union { float f; uint32_t u; } v; v.f = f;
    uint32_t r = (v.u + 0x7FFFu + ((v.u >> 16) & 1u)) >> 16;   // RNE
    return (unsigned short)r;
}
static __device__ __forceinline__ float bf2f(unsigned short b) {
    union { uint32_t u; float f; } v; v.u = ((uint32_t)b) << 16;
    return v.f;
}

static __device__ __forceinline__ void gload16(const short* g, short* l) {
    __builtin_amdgcn_global_load_lds(
        (const __attribute__((address_space(1))) unsigned int*)g,
        (__attribute__((address_space(3))) unsigned int*)l,
        16, 0, 0);
}

// ---------------- prep kernels ----------------

__global__ void k_zero(float* a, float* b, int* c, int n) {
    int i = blockIdx.x * blockDim.x + threadIdx.x;
    if (i < n) { a[i] = 0.f; b[i] = 0.f; c[i] = 0; }
}

__global__ void k_count(const int* __restrict__ src, const int* __restrict__ dst,
                        float* deg_out, float* deg_in, int E) {
    int e = blockIdx.x * blockDim.x + threadIdx.x;
    if (e < E) {
        atomicAdd(&deg_out[src[e]], 1.f);
        atomicAdd(&deg_in[dst[e]], 1.f);
    }
}

__global__ void k_inv(const float* deg_out, const float* deg_in,
                      float* inv_out, float* inv_in, int n) {
    int i = blockIdx.x * blockDim.x + threadIdx.x;
    if (i < n) {
        inv_out[i] = rsqrtf(fmaxf(deg_out[i], 1.f));
        inv_in[i]  = rsqrtf(fmaxf(deg_in[i], 1.f));
    }
}

__global__ void k_scan(const float* __restrict__ deg_in, int* __restrict__ row_off) {
    __shared__ int part[1024];
    const int t = threadIdx.x;
    int v0 = (int)deg_in[t*4+0], v1 = (int)deg_in[t*4+1],
        v2 = (int)deg_in[t*4+2], v3 = (int)deg_in[t*4+3];
    part[t] = v0 + v1 + v2 + v3;
    __syncthreads();
    for (int off = 1; off < 1024; off <<= 1) {
        int x = (t >= off) ? part[t - off] : 0;
        __syncthreads();
        part[t] += x;
        __syncthreads();
    }
    int run = (t == 0) ? 0 : part[t-1];
    row_off[t*4+0] = run; run += v0;
    row_off[t*4+1] = run; run += v1;
    row_off[t*4+2] = run; run += v2;
    row_off[t*4+3] = run; run += v3;
    if (t == 1023) row_off[4096] = run;
}

__global__ void k_fill(const int* __restrict__ src, const int* __restrict__ dst,
                       const int* __restrict__ row_off, int* cursor,
                       int* __restrict__ esrc, int E) {
    int e = blockIdx.x * blockDim.x + threadIdx.x;
    if (e < E) {
        int d = dst[e];
        int p = atomicAdd(&cursor[d], 1);
        esrc[row_off[d] + p] = src[e];
    }
}

__global__ void k_rowsum(const int* __restrict__ row_off, const int* __restrict__ esrc,
                         const float* __restrict__ inv_out, const float* __restrict__ inv_in,
                         float* __restrict__ rowsum) {
    const int node = blockIdx.x, lane = threadIdx.x;
    const int beg = row_off[node], end = row_off[node + 1];
    float s = 0.f;
    for (int p = beg + lane; p < end; p += 64) s += inv_out[esrc[p]];
    #pragma unroll
    for (int off = 32; off; off >>= 1) s += __shfl_down(s, off, 64);
    if (lane == 0) rowsum[node] = s * inv_in[node];
}

__global__ void k_cvt_scale(const float* __restrict__ in, const float* __restrict__ sc,
                            short* __restrict__ out, int n4, int f4) {
    int i = blockIdx.x * blockDim.x + threadIdx.x;
    if (i < n4) {
        const float s = sc[i / f4];
        float4 v = reinterpret_cast<const float4*>(in)[i];
        s4 o;
        o[0] = (short)f2bf(v.x * s); o[1] = (short)f2bf(v.y * s);
        o[2] = (short)f2bf(v.z * s); o[3] = (short)f2bf(v.w * s);
        reinterpret_cast<s4*>(out)[i] = o;
    }
}

// fp32 [R][C] -> bf16 [C][R]; 64(r)x32(c) tile, block (32,8), ushort2 writes
__global__ void k_tr2(const float* __restrict__ in, short* __restrict__ out, int R, int C) {
    __shared__ float tile[64][33];
    const int bc = blockIdx.x * 32, br = blockIdx.y * 64;
    const int tx = threadIdx.x, ty = threadIdx.y;
    #pragma unroll
    for (int dy = 0; dy < 64; dy += 8)
        tile[ty + dy][tx] = in[(size_t)(br + ty + dy) * C + bc + tx];
    __syncthreads();
    #pragma unroll
    for (int dy = 0; dy < 32; dy += 8) {
        const int oy = ty + dy;
        ushort2 o;
        o.x = f2bf(tile[tx * 2][oy]);
        o.y = f2bf(tile[tx * 2 + 1][oy]);
        *reinterpret_cast<ushort2*>(&out[(size_t)(bc + oy) * R + br + tx * 2]) = o;
    }
}

// ---------------- bf16 MFMA GEMM, one-phase-lookahead quadrant pipeline ----------------
// C[M][N] = A[M][K] * Bt^T; A row-major, Bt = B^T row-major [N][K], all bf16.
// EPI==1: out = acc + rs[row]*bias[col]; EPI==2: out = acc * rs[row].
// Tile 256x256, BK=64. 8 waves = 2M x 4N, wave tile 128x64 (quadrants 64x32).
// LDS: 2 buffers x (A[256][64] + B[256][64]) = 128KB; tile t in buf[t&1].
// Register halves: aL(m0-3), aH(m4-7), bL(n0-1), bH(n2-3), each x2 k-slices.
// Phases (per tile t; reads are ONE PHASE AHEAD of their consuming MFMA):
//   P0: ds bH(t) 4           | MFMA Q0 = aL x bL   (aL,bL read last tile)
//   P1: ds aH(t) 8           | MFMA Q1 = aL x bH
//   P2: stage 6 (t+2: B0-3 + A0,A2) ; vmcnt(6) [tile t+1 landed] ;
//       ds aL(t+1) 8 from other buf | MFMA Q2 = aH x bL
//   P3: stage 2 (t+2: A1,A3) ; ds bL(t+1) 4 | MFMA Q3 = aH x bH
// Unit death (staging granularity 64-row units): A_L = units {0,2} dead
// after P1-close (serviced for Q0/Q1); A_H = {1,3} dead after P2-close;
// all B units dead after P1-close (bL serviced for Q0, bH for Q1) => stage
// slots above are race-free (loads land >=1 phase after issue).
// vmcnt(6) leaves exactly t+2's 6 in flight; drain-0 only in last 2 tiles.
// Requires nt >= 2 and M%256==N%256==K%64==0; grid nwg%8==0 (XCD swizzle).
template<int EPI>
__global__ __launch_bounds__(512, 2)
void gemm8p(const short* __restrict__ A, const short* __restrict__ Bt,
            short* __restrict__ C,
            const float* __restrict__ bias, const float* __restrict__ rs,
            int M, int N, int K)
{
    constexpr int USZ  = 4096;            // shorts per 64-row x 64-short unit
    constexpr int BOFF = 4 * USZ;         // B region offset within buffer (16384)
    constexpr int BUF  = 8 * USZ;         // shorts per buffer (32768 = 64KB)
    __shared__ __align__(16) short lds[2 * BUF];   // 128 KB
    const int tid  = threadIdx.x;
    const int wid  = tid >> 6, lane = tid & 63;
    const int wm   = wid >> 2;            // 0..1  (M wave index)
    const int wn   = wid & 3;             // 0..3  (N wave index)
    const int fr   = lane & 15;
    const int kq   = lane >> 4;           // 0..3
    const int nt   = K >> 6;

    // bijective XCD-chunk swizzle (nwg % 8 == 0)
    const int gx  = gridDim.x;
    const int nwg = gx * gridDim.y;
    int bid = blockIdx.y * gx + blockIdx.x;
    bid = (bid & 7) * (nwg >> 3) + (bid >> 3);
    const int tm = (bid / gx) * 256;
    const int tn = (bid % gx) * 256;

    // ---- staging addressing (per thread: 1 gload16 per 8KB unit) ----
    const int srow = tid >> 3;            // 0..63 row within unit
    const int scq  = tid & 7;             // linear 16B-chunk within row
    const int scs  = scq ^ (srow & 7);    // pre-swizzled source chunk
    const short* gA = A  + (size_t)(tm + srow) * K + scs * 8;
    const short* gB = Bt + (size_t)(tn + srow) * K + scs * 8;
    short* const ldst = lds + tid * 8;    // + bufoff + unit*USZ (shorts)

    // ---- fragment read offsets (shorts, lane-constant) ----
    const int cx0 = (0 * 4 + kq) ^ (fr & 7);
    const int cx1 = (1 * 4 + kq) ^ (fr & 7);
    int aoff[8][2], boff[4][2];
    #pragma unroll
    for (int mi = 0; mi < 8; ++mi) {
        const int r = wm * 128 + mi * 16 + fr;
        aoff[mi][0] = r * 64 + cx0 * 8;
        aoff[mi][1] = r * 64 + cx1 * 8;
    }
    #pragma unroll
    for (int n = 0; n < 4; ++n) {
        const int r = wn * 64 + n * 16 + fr;
        boff[n][0] = BOFF + r * 64 + cx0 * 8;
        boff[n][1] = BOFF + r * 64 + cx1 * 8;
    }

    f32x4 acc[8][4];
    #pragma unroll
    for (int mi = 0; mi < 8; ++mi)
        #pragma unroll
        for (int n = 0; n < 4; ++n)
            acc[mi][n] = (f32x4){0.f, 0.f, 0.f, 0.f};

    bf8 aL[4][2], aH[4][2], bL[2][2], bH[2][2];

    // ---- prologue: stage tile 0 -> buf0, tile 1 -> buf1 ----
    #pragma unroll
    for (int u = 0; u < 4; ++u) gload16(gA + (size_t)u * 64 * K, ldst + u * USZ);
    #pragma unroll
    for (int v = 0; v < 4; ++v) gload16(gB + (size_t)v * 64 * K, ldst + BOFF + v * USZ);
    #pragma unroll
    for (int u = 0; u < 4; ++u) gload16(gA + (size_t)u * 64 * K + 64, ldst + BUF + u * USZ);
    #pragma unroll
    for (int v = 0; v < 4; ++v) gload16(gB + (size_t)v * 64 * K + 64, ldst + BUF + BOFF + v * USZ);
    asm volatile("s_waitcnt vmcnt(8)" ::: "memory");   // tile 0 landed; tile 1 in flight
    __builtin_amdgcn_sched_barrier(0);
    __builtin_amdgcn_s_barrier();

    // ---- prime Q0 fragments of tile 0 (aL, bL from buf0) ----
    #pragma unroll
    for (int mi = 0; mi < 4; ++mi)
        #pragma unroll
        for (int s = 0; s < 2; ++s)
            aL[mi][s] = *reinterpret_cast<const bf8*>(lds + aoff[mi][s]);
    #pragma unroll
    for (int n = 0; n < 2; ++n)
        #pragma unroll
        for (int s = 0; s < 2; ++s)
            bL[n][s] = *reinterpret_cast<const bf8*>(lds + boff[n][s]);

    for (int t = 0; t < nt; ++t) {
        const int cc = (t & 1) * BUF;     // tile t's buffer (also stage target for t+2)
        const int cn = cc ^ BUF;          // tile t+1's buffer
        const bool pf = (t + 2 < nt);
        const bool nx = (t + 1 < nt);
        const size_t kf = (size_t)(t + 2) * 64;

        if (!nx) { asm volatile("s_waitcnt vmcnt(0)" ::: "memory"); }  // tail safety

        // ======== P0: ds bH(t); MFMA Q0 = aL x bL ========
        #pragma unroll
        for (int n = 0; n < 2; ++n)
            #pragma unroll
            for (int s = 0; s < 2; ++s)
                bH[n][s] = *reinterpret_cast<const bf8*>(lds + cc + boff[2 + n][s]);
        __builtin_amdgcn_s_barrier();
        __builtin_amdgcn_s_setprio(1);
        #pragma unroll
        for (int mi = 0; mi < 4; ++mi)
            #pragma unroll
            for (int n = 0; n < 2; ++n)
                #pragma unroll
                for (int s = 0; s < 2; ++s)
                    acc[mi][n] = __builtin_amdgcn_mfma_f32_16x16x32_bf16(aL[mi][s], bL[n][s], acc[mi][n], 0, 0, 0);
        __builtin_amdgcn_s_setprio(0);
        __builtin_amdgcn_s_barrier();

        // ======== P1: ds aH(t); MFMA Q1 = aL x bH ========
        #pragma unroll
        for (int mi = 0; mi < 4; ++mi)
            #pragma unroll
            for (int s = 0; s < 2; ++s)
                aH[mi][s] = *reinterpret_cast<const bf8*>(lds + cc + aoff[4 + mi][s]);
        __builtin_amdgcn_s_barrier();
        __builtin_amdgcn_s_setprio(1);
        #pragma unroll
        for (int mi = 0; mi < 4; ++mi)
            #pragma unroll
            for (int n = 0; n < 2; ++n)
                #pragma unroll
                for (int s = 0; s < 2; ++s)
                    acc[mi][2 + n] = __builtin_amdgcn_mfma_f32_16x16x32_bf16(aL[mi][s], bH[n][s], acc[mi][2 + n], 0, 0, 0);
        __builtin_amdgcn_s_setprio(0);
        __builtin_amdgcn_s_barrier();

        // ======== P2: stage 6 (t+2); vmcnt(6); ds aL(t+1); MFMA Q2 = aH x bL ========
        if (pf) {
            #pragma unroll
            for (int v = 0; v < 4; ++v)
                gload16(gB + (size_t)v * 64 * K + kf, ldst + cc + BOFF + v * USZ);
            gload16(gA + (size_t)0 * 64 * K + kf, ldst + cc + 0 * USZ);
            gload16(gA + (size_t)2 * 64 * K + kf, ldst + cc + 2 * USZ);
            asm volatile("s_waitcnt vmcnt(6)" ::: "memory");   // t+1 fully landed
        } else {
            asm volatile("s_waitcnt vmcnt(0)" ::: "memory");
        }
        if (nx) {
            #pragma unroll
            for (int mi = 0; mi < 4; ++mi)
                #pragma unroll
                for (int s = 0; s < 2; ++s)
                    aL[mi][s] = *reinterpret_cast<const bf8*>(lds + cn + aoff[mi][s]);
        }
        __builtin_amdgcn_s_barrier();
        __builtin_amdgcn_s_setprio(1);
        #pragma unroll
        for (int mi = 0; mi < 4; ++mi)
            #pragma unroll
            for (int n = 0; n < 2; ++n)
                #pragma unroll
                for (int s = 0; s < 2; ++s)
                    acc[4 + mi][n] = __builtin_amdgcn_mfma_f32_16x16x32_bf16(aH[mi][s], bL[n][s], acc[4 + mi][n], 0, 0, 0);
        __builtin_amdgcn_s_setprio(0);
        __builtin_amdgcn_s_barrier();

        // ======== P3: stage 2 (t+2); ds bL(t+1); MFMA Q3 = aH x bH ========
        if (pf) {
            gload16(gA + (size_t)1 * 64 * K + kf, ldst + cc + 1 * USZ);
            gload16(gA + (size_t)3 * 64 * K + kf, ldst + cc + 3 * USZ);
        }
        if (nx) {
            #pragma unroll
            for (int n = 0; n < 2; ++n)
                #pragma unroll
                for (int s = 0; s < 2; ++s)
                    bL[n][s] = *reinterpret_cast<const bf8*>(lds + cn + boff[n][s]);
        }
        __builtin_amdgcn_s_barrier();
        __builtin_amdgcn_s_setprio(1);
        #pragma unroll
        for (int mi = 0; mi < 4; ++mi)
            #pragma unroll
            for (int n = 0; n < 2; ++n)
                #pragma unroll
                for (int s = 0; s < 2; ++s)
                    acc[4 + mi][2 + n] = __builtin_amdgcn_mfma_f32_16x16x32_bf16(aH[mi][s], bH[n][s], acc[4 + mi][2 + n], 0, 0, 0);
        __builtin_amdgcn_s_setprio(0);
        __builtin_amdgcn_s_barrier();
    }

    // ---- epilogue: C/D layout col = lane&15, row = (lane>>4)*4 + reg ----
    const int rb = kq * 4;
    #pragma unroll
    for (int mi = 0; mi < 8; ++mi) {
        #pragma unroll
        for (int n = 0; n < 4; ++n) {
            const int col = tn + wn * 64 + n * 16 + fr;
            const float bcol = (EPI == 1) ? bias[col] : 0.f;
            #pragma unroll
            for (int j = 0; j < 4; ++j) {
                const int row = tm + wm * 128 + mi * 16 + rb + j;
                float v = acc[mi][n][j];
                if (EPI == 1) v += rs[row] * bcol;
                else          v *= rs[row];
                C[(size_t)row * N + col] = (short)f2bf(v);
            }
        }
    }
}

// ---------------- CSR aggregation, L2-striped ----------------
// Y[i] = inv_in[i] * sum_{e: dst=i} X[src[e]].  512-col stripe (4 MB of X at
// F=4096) pinned to one XCD: linear bid % 8 == blockIdx.x == stripe, and
// dispatch round-robins linear bid across XCDs. 64-thread blocks.
template<int RELU>
__global__ __launch_bounds__(64)
void agg_strip(const short* __restrict__ X, short* __restrict__ Y,
               const int* __restrict__ row_off, const int* __restrict__ esrc,
               const float* __restrict__ inv_in, int F)
{
    const int node = blockIdx.y;
    const int c0 = blockIdx.x * 512 + threadIdx.x * 8;
    float acc[8];
    #pragma unroll
    for (int j = 0; j < 8; ++j) acc[j] = 0.f;

    const int beg = row_off[node], end = row_off[node + 1];
    int p = beg;
    for (; p + 3 < end; p += 4) {
        const int s0 = esrc[p], s1 = esrc[p + 1], s2 = esrc[p + 2], s3 = esrc[p + 3];
        bf8 x0 = *reinterpret_cast<const bf8*>(X + (size_t)s0 * F + c0);
        bf8 x1 = *reinterpret_cast<const bf8*>(X + (size_t)s1 * F + c0);
        bf8 x2 = *reinterpret_cast<const bf8*>(X + (size_t)s2 * F + c0);
        bf8 x3 = *reinterpret_cast<const bf8*>(X + (size_t)s3 * F + c0);
        #pragma unroll
        for (int j = 0; j < 8; ++j)
            acc[j] += (bf2f((unsigned short)x0[j]) + bf2f((unsigned short)x1[j]))
                    + (bf2f((unsigned short)x2[j]) + bf2f((unsigned short)x3[j]));
    }
    for (; p < end; ++p) {
        const int s0 = esrc[p];
        bf8 x0 = *reinterpret_cast<const bf8*>(X + (size_t)s0 * F + c0);
        #pragma unroll
        for (int j = 0; j < 8; ++j) acc[j] += bf2f((unsigned short)x0[j]);
    }
    const float sc = inv_in[node];
    bf8 o;
    #pragma unroll
    for (int j = 0; j < 8; ++j) {
        float v = acc[j] * sc;
        if (RELU) v = fmaxf(v, 0.f);
        o[j] = (short)f2bf(v);
    }
    *reinterpret_cast<bf8*>(Y + (size_t)node * F + c0) = o;
}

// ---------------- head: logits = H[4096] . Wl[4096][16] + bl; softmax ----------------
__global__ __launch_bounds__(256)
void k_head(const short* __restrict__ H, const float* __restrict__ Wl,
            const float* __restrict__ bl, float* __restrict__ out)
{
    const int row = blockIdx.x;
    const int tid = threadIdx.x;
    float acc[16];
    #pragma unroll
    for (int c = 0; c < 16; ++c) acc[c] = 0.f;

    for (int k = tid; k < 4096; k += 256) {
        const float x = bf2f((unsigned short)H[(size_t)row * 4096 + k]);
        const float4* w = reinterpret_cast<const float4*>(Wl + (size_t)k * 16);
        float4 w0 = w[0], w1 = w[1], w2 = w[2], w3 = w[3];
        acc[0]  += x * w0.x; acc[1]  += x * w0.y; acc[2]  += x * w0.z; acc[3]  += x * w0.w;
        acc[4]  += x * w1.x; acc[5]  += x * w1.y; acc[6]  += x * w1.z; acc[7]  += x * w1.w;
        acc[8]  += x * w2.x; acc[9]  += x * w2.y; acc[10] += x * w2.z; acc[11] += x * w2.w;
        acc[12] += x * w3.x; acc[13] += x * w3.y; acc[14] += x * w3.z; acc[15] += x * w3.w;
    }
    #pragma unroll
    for (int c = 0; c < 16; ++c)
        for (int off = 32; off; off >>= 1)
            acc[c] += __shfl_down(acc[c], off, 64);

    __shared__ float sm[16][4];
    const int wid = tid >> 6, lane = tid & 63;
    if (lane == 0) {
        #pragma unroll
        for (int c = 0; c < 16; ++c) sm[c][wid] = acc[c];
    }
    __syncthreads();
    if (tid < 16) {
        float l = sm[tid][0] + sm[tid][1] + sm[tid][2] + sm[tid][3] + bl[tid];
        float mx = l;
        #pragma unroll
        for (int off = 1; off < 16; off <<= 1) mx = fmaxf(mx, __shfl_xor(mx, off, 16));
        float e = expf(l - mx);
        float s = e;
        #pragma unroll
        for (int off = 1; off < 16; off <<= 1) s += __shfl_xor(s, off, 16);
        out[(size_t)row * 16 + tid] = e / s;
    }
}

// ---------------- launch ----------------

extern "C" void kernel_launch(void* const* d_in, const int* in_sizes, int n_in,
                              void* d_out, int out_size, void* d_ws, size_t ws_size,
                              hipStream_t stream)
{
    const float* features = (const float*)d_in[0];
    const float* W1       = (const float*)d_in[1];
    const float* b1       = (const float*)d_in[2];
    const float* W2       = (const float*)d_in[3];
    const float* Wl       = (const float*)d_in[4];
    const float* bl       = (const float*)d_in[5];
    const int*   src      = (const int*)d_in[6];
    const int*   dst      = (const int*)d_in[7];
    float* out = (float*)d_out;

    const int N = 4096, IN = 512, H = 8192;
    const int E = in_sizes[6];

    char* ws = (char*)d_ws;
    size_t o = 0;
    auto alloc = [&](size_t bytes) -> char* {
        char* p = ws + o;
        o = (o + bytes + 255) & ~(size_t)255;
        return p;
    };
    short* W2t   = (short*)alloc((size_t)N * H * 2);     // 64 MB  W2^T bf16 [4096][8192]
    short* h1    = (short*)alloc((size_t)N * H * 2);     // 64 MB  conv1 out bf16 [4096][8192]
    short* x2s   = (short*)alloc((size_t)N * N * 2);     // 32 MB  (h1 W2)*inv_out bf16
    short* featb = (short*)alloc((size_t)N * IN * 2);    // 4 MB   features*inv_out bf16
    short* aggF  = (short*)alloc((size_t)N * IN * 2);    // 4 MB   A_hat X bf16
    short* W1t   = (short*)alloc((size_t)H * IN * 2);    // 8 MB   W1^T bf16 [8192][512]
    float* deg_out = (float*)alloc(N * 4);
    float* deg_in  = (float*)alloc(N * 4);
    float* inv_out = (float*)alloc(N * 4);
    float* inv_in  = (float*)alloc(N * 4);
    float* rowsum  = (float*)alloc(N * 4);
    int*   cursor  = (int*)alloc(N * 4);
    int*   row_off = (int*)alloc((N + 1) * 4);
    int*   esrc    = (int*)alloc((size_t)E * 4);
    short* h2 = h1;   // alias: h1 dead after GEMM2, h2 written by agg2

    // graph prep
    k_zero <<<(N + 255) / 256, 256, 0, stream>>>(deg_out, deg_in, cursor, N);
    k_count<<<(E + 255) / 256, 256, 0, stream>>>(src, dst, deg_out, deg_in, E);
    k_inv  <<<(N + 255) / 256, 256, 0, stream>>>(deg_out, deg_in, inv_out, inv_in, N);
    k_scan <<<1, 1024, 0, stream>>>(deg_in, row_off);
    k_fill <<<(E + 255) / 256, 256, 0, stream>>>(src, dst, row_off, cursor, esrc, E);
    k_rowsum<<<N, 64, 0, stream>>>(row_off, esrc, inv_out, inv_in, rowsum);

    // operand conversion
    k_cvt_scale<<<(N * IN / 4 + 255) / 256, 256, 0, stream>>>(features, inv_out, featb,
                                                              N * IN / 4, IN / 4);
    k_tr2<<<dim3(H / 32, IN / 64), dim3(32, 8), 0, stream>>>(W1, W1t, IN, H);
    k_tr2<<<dim3(N / 32, H / 64), dim3(32, 8), 0, stream>>>(W2, W2t, H, N);

    // conv1: aggregate features first (F=512), then GEMM1 with rowsum*b1 epilogue
    agg_strip<0><<<dim3(1, N), 64, 0, stream>>>(featb, aggF, row_off, esrc, inv_in, IN);
    gemm8p<1><<<dim3(H / 256, N / 256), 512, 0, stream>>>(aggF, W1t, h1, b1, rowsum, N, H, IN);

    // conv2: project first, then aggregate (L2-striped: stripe = bid%8 = XCD)
    gemm8p<2><<<dim3(N / 256, N / 256), 512, 0, stream>>>(h1, W2t, x2s, nullptr, inv_out, N, N, H);
    agg_strip<1><<<dim3(N / 512, N), 64, 0, stream>>>(x2s, h2, row_off, esrc, inv_in, N);

    // head + softmax
    k_head<<<N, 256, 0, stream>>>(h2, Wl, bl, out);
}

// Round 9
// 434.154 us; speedup vs baseline: 1.1370x; 1.1370x over previous
//
#include <hip/hip_runtime.h>
#include <cstdint>
#include <cstddef>

// ---------------------------------------------------------------------------
// GCN forward:  softmax( (A_hat relu(A_hat (X W1 + b1) W2)) Wl + bl )
// conv1 reordered: aggregate features (F=512) first, GEMM1 epilogue adds
// rowsum*b1. conv2: project (8192->4096) then aggregate.
// GEMM: R6 kernel (best measured: 261us, MfmaUtil 47%): 256x256, BK=64,
// 8 waves, 2-buffer LDS with same-buffer region ring, counted vmcnt(8),
// 4x16-MFMA pinned phases, T2 XOR swizzle, T5 setprio, XCD swizzle.
// R9: k_head (1GB L2 Wl re-read, ~32us) replaced by split-K MFMA head-GEMM
// (Wl^T staged once per block, partials -> logitsP, no atomics) + tiny
// reduce+softmax kernel.
// ---------------------------------------------------------------------------

using bf8   = __attribute__((ext_vector_type(8))) short;   // 8 bf16 (4 VGPR)
using s4    = __attribute__((ext_vector_type(4))) short;
using f32x4 = __attribute__((ext_vector_type(4))) float;

static __device__ __forceinline__ unsigned short f2bf(float f) {
    union { float f; uint32_t u; } v; v.f = f;
    uint32_t r = (v.u + 0x7FFFu + ((v.u >> 16) & 1u)) >> 16;   // RNE
    return (unsigned short)r;
}
static __device__ __forceinline__ float bf2f(unsigned short b) {
    union { uint32_t u; float f; } v; v.u = ((uint32_t)b) << 16;
    return v.f;
}

static __device__ __forceinline__ void gload16(const short* g, short* l) {
    __builtin_amdgcn_global_load_lds(
        (const __attribute__((address_space(1))) unsigned int*)g,
        (__attribute__((address_space(3))) unsigned int*)l,
        16, 0, 0);
}

// ---------------- prep kernels ----------------

__global__ void k_zero(float* a, float* b, int* c, int n) {
    int i = blockIdx.x * blockDim.x + threadIdx.x;
    if (i < n) { a[i] = 0.f; b[i] = 0.f; c[i] = 0; }
}

__global__ void k_count(const int* __restrict__ src, const int* __restrict__ dst,
                        float* deg_out, float* deg_in, int E) {
    int e = blockIdx.x * blockDim.x + threadIdx.x;
    if (e < E) {
        atomicAdd(&deg_out[src[e]], 1.f);
        atomicAdd(&deg_in[dst[e]], 1.f);
    }
}

__global__ void k_inv(const float* deg_out, const float* deg_in,
                      float* inv_out, float* inv_in, int n) {
    int i = blockIdx.x * blockDim.x + threadIdx.x;
    if (i < n) {
        inv_out[i] = rsqrtf(fmaxf(deg_out[i], 1.f));
        inv_in[i]  = rsqrtf(fmaxf(deg_in[i], 1.f));
    }
}

__global__ void k_scan(const float* __restrict__ deg_in, int* __restrict__ row_off) {
    __shared__ int part[1024];
    const int t = threadIdx.x;
    int v0 = (int)deg_in[t*4+0], v1 = (int)deg_in[t*4+1],
        v2 = (int)deg_in[t*4+2], v3 = (int)deg_in[t*4+3];
    part[t] = v0 + v1 + v2 + v3;
    __syncthreads();
    for (int off = 1; off < 1024; off <<= 1) {
        int x = (t >= off) ? part[t - off] : 0;
        __syncthreads();
        part[t] += x;
        __syncthreads();
    }
    int run = (t == 0) ? 0 : part[t-1];
    row_off[t*4+0] = run; run += v0;
    row_off[t*4+1] = run; run += v1;
    row_off[t*4+2] = run; run += v2;
    row_off[t*4+3] = run; run += v3;
    if (t == 1023) row_off[4096] = run;
}

__global__ void k_fill(const int* __restrict__ src, const int* __restrict__ dst,
                       const int* __restrict__ row_off, int* cursor,
                       int* __restrict__ esrc, int E) {
    int e = blockIdx.x * blockDim.x + threadIdx.x;
    if (e < E) {
        int d = dst[e];
        int p = atomicAdd(&cursor[d], 1);
        esrc[row_off[d] + p] = src[e];
    }
}

__global__ void k_rowsum(const int* __restrict__ row_off, const int* __restrict__ esrc,
                         const float* __restrict__ inv_out, const float* __restrict__ inv_in,
                         float* __restrict__ rowsum) {
    const int node = blockIdx.x, lane = threadIdx.x;
    const int beg = row_off[node], end = row_off[node + 1];
    float s = 0.f;
    for (int p = beg + lane; p < end; p += 64) s += inv_out[esrc[p]];
    #pragma unroll
    for (int off = 32; off; off >>= 1) s += __shfl_down(s, off, 64);
    if (lane == 0) rowsum[node] = s * inv_in[node];
}

__global__ void k_cvt_scale(const float* __restrict__ in, const float* __restrict__ sc,
                            short* __restrict__ out, int n4, int f4) {
    int i = blockIdx.x * blockDim.x + threadIdx.x;
    if (i < n4) {
        const float s = sc[i / f4];
        float4 v = reinterpret_cast<const float4*>(in)[i];
        s4 o;
        o[0] = (short)f2bf(v.x * s); o[1] = (short)f2bf(v.y * s);
        o[2] = (short)f2bf(v.z * s); o[3] = (short)f2bf(v.w * s);
        reinterpret_cast<s4*>(out)[i] = o;
    }
}

// fp32 [R][C] -> bf16 [C][R]; 64(r)x32(c) tile, block (32,8), ushort2 writes
__global__ void k_tr2(const float* __restrict__ in, short* __restrict__ out, int R, int C) {
    __shared__ float tile[64][33];
    const int bc = blockIdx.x * 32, br = blockIdx.y * 64;
    const int tx = threadIdx.x, ty = threadIdx.y;
    #pragma unroll
    for (int dy = 0; dy < 64; dy += 8)
        tile[ty + dy][tx] = in[(size_t)(br + ty + dy) * C + bc + tx];
    __syncthreads();
    #pragma unroll
    for (int dy = 0; dy < 32; dy += 8) {
        const int oy = ty + dy;
        ushort2 o;
        o.x = f2bf(tile[tx * 2][oy]);
        o.y = f2bf(tile[tx * 2 + 1][oy]);
        *reinterpret_cast<ushort2*>(&out[(size_t)(bc + oy) * R + br + tx * 2]) = o;
    }
}

// ---------------- bf16 MFMA GEMM, 4-phase counted-vmcnt pipeline (R6) ----------------
// C[M][N] = A[M][K] * Bt^T; A row-major, Bt = B^T row-major [N][K], all bf16.
// EPI==1: out = acc + rs[row]*bias[col]; EPI==2: out = acc * rs[row].
// Tile 256x256, BK=64. 8 waves = 2M x 4N, wave tile 128x64.
// LDS: 2 buffers x (A[256][64] + B[256][64]) = 128KB; tile t in buf[t&1].
// Stage of tile t+2 goes into buf[t&1] using region-death ordering (B dead
// after P1, A dead after P2). vmcnt(8) at tile end: t+1 landed, t+2's 8 in
// flight (never drains in steady state). T2 XOR swizzle both sides.
// Requires nt >= 2 and M%256==N%256==K%64==0; grid nwg%8==0 (XCD swizzle).
template<int EPI>
__global__ __launch_bounds__(512, 2)
void gemm8p(const short* __restrict__ A, const short* __restrict__ Bt,
            short* __restrict__ C,
            const float* __restrict__ bias, const float* __restrict__ rs,
            int M, int N, int K)
{
    constexpr int USZ  = 4096;            // shorts per 64-row x 64-short unit
    constexpr int BOFF = 4 * USZ;         // B region offset within buffer (16384)
    constexpr int BUF  = 8 * USZ;         // shorts per buffer (32768 = 64KB)
    __shared__ __align__(16) short lds[2 * BUF];   // 128 KB
    const int tid  = threadIdx.x;
    const int wid  = tid >> 6, lane = tid & 63;
    const int wm   = wid >> 2;            // 0..1  (M wave index)
    const int wn   = wid & 3;             // 0..3  (N wave index)
    const int fr   = lane & 15;
    const int kq   = lane >> 4;           // 0..3
    const int nt   = K >> 6;

    // bijective XCD-chunk swizzle (nwg % 8 == 0)
    const int gx  = gridDim.x;
    const int nwg = gx * gridDim.y;
    int bid = blockIdx.y * gx + blockIdx.x;
    bid = (bid & 7) * (nwg >> 3) + (bid >> 3);
    const int tm = (bid / gx) * 256;
    const int tn = (bid % gx) * 256;

    // ---- staging addressing (per thread: 1 gload16 per 8KB unit) ----
    const int srow = tid >> 3;            // 0..63 row within unit
    const int scq  = tid & 7;             // linear 16B-chunk within row
    const int scs  = scq ^ (srow & 7);    // pre-swizzled source chunk
    const short* gA = A  + (size_t)(tm + srow) * K + scs * 8;
    const short* gB = Bt + (size_t)(tn + srow) * K + scs * 8;
    short* const ldst = lds + tid * 8;    // + bufoff + unit*USZ (shorts)

    // ---- fragment read offsets (shorts, lane-constant) ----
    const int cx0 = (0 * 4 + kq) ^ (fr & 7);
    const int cx1 = (1 * 4 + kq) ^ (fr & 7);
    int aoff[8][2], boff[4][2];
    #pragma unroll
    for (int mi = 0; mi < 8; ++mi) {
        const int r = wm * 128 + mi * 16 + fr;
        aoff[mi][0] = r * 64 + cx0 * 8;
        aoff[mi][1] = r * 64 + cx1 * 8;
    }
    #pragma unroll
    for (int n = 0; n < 4; ++n) {
        const int r = wn * 64 + n * 16 + fr;
        boff[n][0] = BOFF + r * 64 + cx0 * 8;
        boff[n][1] = BOFF + r * 64 + cx1 * 8;
    }

    f32x4 acc[8][4];
    #pragma unroll
    for (int mi = 0; mi < 8; ++mi)
        #pragma unroll
        for (int n = 0; n < 4; ++n)
            acc[mi][n] = (f32x4){0.f, 0.f, 0.f, 0.f};

    // ---- prologue: stage tile 0 -> buf0, tile 1 -> buf1; wait tile 0 ----
    #pragma unroll
    for (int u = 0; u < 4; ++u) gload16(gA + (size_t)u * 64 * K, ldst + u * USZ);
    #pragma unroll
    for (int v = 0; v < 4; ++v) gload16(gB + (size_t)v * 64 * K, ldst + BOFF + v * USZ);
    #pragma unroll
    for (int u = 0; u < 4; ++u) gload16(gA + (size_t)u * 64 * K + 64, ldst + BUF + u * USZ);
    #pragma unroll
    for (int v = 0; v < 4; ++v) gload16(gB + (size_t)v * 64 * K + 64, ldst + BUF + BOFF + v * USZ);
    asm volatile("s_waitcnt vmcnt(8)" ::: "memory");   // tile 0 landed
    __builtin_amdgcn_sched_barrier(0);
    __builtin_amdgcn_s_barrier();

    for (int t = 0; t < nt; ++t) {
        const int cc = (t & 1) * BUF;          // compute buffer == stage target for t+2
        const bool pf = (t + 2 < nt);
        const size_t kf = (size_t)(t + 2) * 64;

        bf8 a03[4][2], a47[4][2], bg[4][2];

        // ---- P0: read A m0-3 (8) + B n0-1 (4); 16 MFMA (m0-3 x n0-1) ----
        #pragma unroll
        for (int mi = 0; mi < 4; ++mi)
            #pragma unroll
            for (int s = 0; s < 2; ++s)
                a03[mi][s] = *reinterpret_cast<const bf8*>(lds + cc + aoff[mi][s]);
        #pragma unroll
        for (int n = 0; n < 2; ++n)
            #pragma unroll
            for (int s = 0; s < 2; ++s)
                bg[n][s] = *reinterpret_cast<const bf8*>(lds + cc + boff[n][s]);
        __builtin_amdgcn_s_barrier();
        asm volatile("s_waitcnt lgkmcnt(0)" ::: "memory");
        __builtin_amdgcn_sched_barrier(0);
        __builtin_amdgcn_s_setprio(1);
        #pragma unroll
        for (int mi = 0; mi < 4; ++mi)
            #pragma unroll
            for (int n = 0; n < 2; ++n)
                #pragma unroll
                for (int s = 0; s < 2; ++s)
                    acc[mi][n] = __builtin_amdgcn_mfma_f32_16x16x32_bf16(a03[mi][s], bg[n][s], acc[mi][n], 0, 0, 0);
        __builtin_amdgcn_s_setprio(0);
        __builtin_amdgcn_s_barrier();

        // ---- P1: read B n2-3 (4); 16 MFMA (m0-3 x n2-3) ----
        #pragma unroll
        for (int n = 2; n < 4; ++n)
            #pragma unroll
            for (int s = 0; s < 2; ++s)
                bg[n][s] = *reinterpret_cast<const bf8*>(lds + cc + boff[n][s]);
        __builtin_amdgcn_s_barrier();
        asm volatile("s_waitcnt lgkmcnt(0)" ::: "memory");
        __builtin_amdgcn_sched_barrier(0);
        __builtin_amdgcn_s_setprio(1);
        #pragma unroll
        for (int mi = 0; mi < 4; ++mi)
            #pragma unroll
            for (int n = 2; n < 4; ++n)
                #pragma unroll
                for (int s = 0; s < 2; ++s)
                    acc[mi][n] = __builtin_amdgcn_mfma_f32_16x16x32_bf16(a03[mi][s], bg[n][s], acc[mi][n], 0, 0, 0);
        __builtin_amdgcn_s_setprio(0);
        __builtin_amdgcn_s_barrier();
        // B region of tile t now dead (frags reg-cached) => safe to overwrite.

        // ---- P2: read A m4-7 (8); stage B(t+2) into cc; 16 MFMA (m4-7 x n0-1) ----
        #pragma unroll
        for (int mi = 0; mi < 4; ++mi)
            #pragma unroll
            for (int s = 0; s < 2; ++s)
                a47[mi][s] = *reinterpret_cast<const bf8*>(lds + cc + aoff[4 + mi][s]);
        if (pf) {
            #pragma unroll
            for (int v = 0; v < 4; ++v)
                gload16(gB + (size_t)v * 64 * K + kf, ldst + cc + BOFF + v * USZ);
        }
        __builtin_amdgcn_s_barrier();
        asm volatile("s_waitcnt lgkmcnt(0)" ::: "memory");
        __builtin_amdgcn_sched_barrier(0);
        __builtin_amdgcn_s_setprio(1);
        #pragma unroll
        for (int mi = 0; mi < 4; ++mi)
            #pragma unroll
            for (int n = 0; n < 2; ++n)
                #pragma unroll
                for (int s = 0; s < 2; ++s)
                    acc[4 + mi][n] = __builtin_amdgcn_mfma_f32_16x16x32_bf16(a47[mi][s], bg[n][s], acc[4 + mi][n], 0, 0, 0);
        __builtin_amdgcn_s_setprio(0);
        __builtin_amdgcn_s_barrier();
        // A region of tile t now dead => safe to overwrite.

        // ---- P3: stage A(t+2) into cc; 16 MFMA (m4-7 x n2-3); counted wait ----
        if (pf) {
            #pragma unroll
            for (int u = 0; u < 4; ++u)
                gload16(gA + (size_t)u * 64 * K + kf, ldst + cc + u * USZ);
        }
        __builtin_amdgcn_s_setprio(1);
        #pragma unroll
        for (int mi = 0; mi < 4; ++mi)
            #pragma unroll
            for (int n = 2; n < 4; ++n)
                #pragma unroll
                for (int s = 0; s < 2; ++s)
                    acc[4 + mi][2 + (n - 2)] = acc[4 + mi][n];   // no-op shape keeper (optimized out)
        #pragma unroll
        for (int mi = 0; mi < 4; ++mi)
            #pragma unroll
            for (int n = 2; n < 4; ++n)
                #pragma unroll
                for (int s = 0; s < 2; ++s)
                    acc[4 + mi][n] = __builtin_amdgcn_mfma_f32_16x16x32_bf16(a47[mi][s], bg[n][s], acc[4 + mi][n], 0, 0, 0);
        __builtin_amdgcn_s_setprio(0);
        if (pf) {
            asm volatile("s_waitcnt vmcnt(8)" ::: "memory");   // t+1 landed; t+2 in flight
        } else if (t + 2 == nt) {
            asm volatile("s_waitcnt vmcnt(0)" ::: "memory");   // last prefetched tile
        }
        __builtin_amdgcn_sched_barrier(0);
        __builtin_amdgcn_s_barrier();
    }

    // ---- epilogue: C/D layout col = lane&15, row = (lane>>4)*4 + reg ----
    const int rb = kq * 4;
    #pragma unroll
    for (int mi = 0; mi < 8; ++mi) {
        #pragma unroll
        for (int n = 0; n < 4; ++n) {
            const int col = tn + wn * 64 + n * 16 + fr;
            const float bcol = (EPI == 1) ? bias[col] : 0.f;
            #pragma unroll
            for (int j = 0; j < 4; ++j) {
                const int row = tm + wm * 128 + mi * 16 + rb + j;
                float v = acc[mi][n][j];
                if (EPI == 1) v += rs[row] * bcol;
                else          v *= rs[row];
                C[(size_t)row * N + col] = (short)f2bf(v);
            }
        }
    }
}

// ---------------- CSR aggregation, L2-striped ----------------
template<int RELU>
__global__ __launch_bounds__(64)
void agg_strip(const short* __restrict__ X, short* __restrict__ Y,
               const int* __restrict__ row_off, const int* __restrict__ esrc,
               const float* __restrict__ inv_in, int F)
{
    const int node = blockIdx.y;
    const int c0 = blockIdx.x * 512 + threadIdx.x * 8;
    float acc[8];
    #pragma unroll
    for (int j = 0; j < 8; ++j) acc[j] = 0.f;

    const int beg = row_off[node], end = row_off[node + 1];
    int p = beg;
    for (; p + 3 < end; p += 4) {
        const int s0 = esrc[p], s1 = esrc[p + 1], s2 = esrc[p + 2], s3 = esrc[p + 3];
        bf8 x0 = *reinterpret_cast<const bf8*>(X + (size_t)s0 * F + c0);
        bf8 x1 = *reinterpret_cast<const bf8*>(X + (size_t)s1 * F + c0);
        bf8 x2 = *reinterpret_cast<const bf8*>(X + (size_t)s2 * F + c0);
        bf8 x3 = *reinterpret_cast<const bf8*>(X + (size_t)s3 * F + c0);
        #pragma unroll
        for (int j = 0; j < 8; ++j)
            acc[j] += (bf2f((unsigned short)x0[j]) + bf2f((unsigned short)x1[j]))
                    + (bf2f((unsigned short)x2[j]) + bf2f((unsigned short)x3[j]));
    }
    for (; p < end; ++p) {
        const int s0 = esrc[p];
        bf8 x0 = *reinterpret_cast<const bf8*>(X + (size_t)s0 * F + c0);
        #pragma unroll
        for (int j = 0; j < 8; ++j) acc[j] += bf2f((unsigned short)x0[j]);
    }
    const float sc = inv_in[node];
    bf8 o;
    #pragma unroll
    for (int j = 0; j < 8; ++j) {
        float v = acc[j] * sc;
        if (RELU) v = fmaxf(v, 0.f);
        o[j] = (short)f2bf(v);
    }
    *reinterpret_cast<bf8*>(Y + (size_t)node * F + c0) = o;
}

// ---------------- head-GEMM: logitsP[kc] = H[256-tile] x Wl[512-chunk] ----------------
// H bf16 [4096][4096]; Wl fp32 [4096][16]. Grid (M/256, K/512), 256 thr
// (4 waves x 64 rows). Wl^T chunk staged to LDS as bf16 [16][512] with
// row stride 520 shorts (bank-spread). A-frags read direct from global
// (dense 16-row x 64B pattern, L1-cached, each element read once).
__global__ __launch_bounds__(256)
void k_headgemm(const short* __restrict__ H, const float* __restrict__ Wl,
                float* __restrict__ logitsP)
{
    constexpr int RS = 520;               // LDS row stride in shorts (1040B)
    __shared__ __align__(16) short ldsB[16 * RS];
    const int tid = threadIdx.x;
    const int m0  = blockIdx.x * 256;
    const int k0  = blockIdx.y * 512;
    const int wid = tid >> 6, lane = tid & 63;
    const int fr  = lane & 15;            // class (output col)
    const int kq  = lane >> 4;            // 0..3

    // stage Wl^T[16][512] -> bf16 LDS: thread (c = tid&15, kk = tid>>4)
    {
        const int c = tid & 15, kk = tid >> 4;
        #pragma unroll
        for (int j = 0; j < 32; ++j) {
            const int k = kk * 32 + j;
            ldsB[c * RS + k] = (short)f2bf(Wl[(size_t)(k0 + k) * 16 + c]);
        }
    }
    __syncthreads();

    const int rb0 = m0 + wid * 64;
    f32x4 acc[4];
    #pragma unroll
    for (int mi = 0; mi < 4; ++mi) acc[mi] = (f32x4){0.f, 0.f, 0.f, 0.f};

    #pragma unroll 4
    for (int s = 0; s < 16; ++s) {        // k-slices of 32
        const bf8 b = *reinterpret_cast<const bf8*>(ldsB + fr * RS + s * 32 + kq * 8);
        #pragma unroll
        for (int mi = 0; mi < 4; ++mi) {
            const bf8 a = *reinterpret_cast<const bf8*>(
                H + (size_t)(rb0 + mi * 16 + fr) * 4096 + k0 + s * 32 + kq * 8);
            acc[mi] = __builtin_amdgcn_mfma_f32_16x16x32_bf16(a, b, acc[mi], 0, 0, 0);
        }
    }

    // C/D: col = fr (class), row = kq*4 + j
    float* outP = logitsP + (size_t)blockIdx.y * 4096 * 16;
    #pragma unroll
    for (int mi = 0; mi < 4; ++mi)
        #pragma unroll
        for (int j = 0; j < 4; ++j)
            outP[(size_t)(rb0 + mi * 16 + kq * 4 + j) * 16 + fr] = acc[mi][j];
}

// ---------------- reduce partials + bias + softmax ----------------
__global__ __launch_bounds__(64)
void k_soft(const float* __restrict__ logitsP, const float* __restrict__ bl,
            float* __restrict__ out)
{
    const int node = blockIdx.x * 64 + threadIdx.x;
    float l[16];
    #pragma unroll
    for (int c = 0; c < 16; ++c) l[c] = bl[c];
    for (int p = 0; p < 8; ++p) {
        const float4* lp = reinterpret_cast<const float4*>(
            logitsP + ((size_t)p * 4096 + node) * 16);
        #pragma unroll
        for (int q = 0; q < 4; ++q) {
            float4 v = lp[q];
            l[q*4+0] += v.x; l[q*4+1] += v.y; l[q*4+2] += v.z; l[q*4+3] += v.w;
        }
    }
    float mx = l[0];
    #pragma unroll
    for (int c = 1; c < 16; ++c) mx = fmaxf(mx, l[c]);
    float s = 0.f;
    #pragma unroll
    for (int c = 0; c < 16; ++c) { l[c] = expf(l[c] - mx); s += l[c]; }
    const float inv = 1.f / s;
    float4* o = reinterpret_cast<float4*>(out + (size_t)node * 16);
    #pragma unroll
    for (int q = 0; q < 4; ++q)
        o[q] = make_float4(l[q*4+0]*inv, l[q*4+1]*inv, l[q*4+2]*inv, l[q*4+3]*inv);
}

// ---------------- launch ----------------

extern "C" void kernel_launch(void* const* d_in, const int* in_sizes, int n_in,
                              void* d_out, int out_size, void* d_ws, size_t ws_size,
                              hipStream_t stream)
{
    const float* features = (const float*)d_in[0];
    const float* W1       = (const float*)d_in[1];
    const float* b1       = (const float*)d_in[2];
    const float* W2       = (const float*)d_in[3];
    const float* Wl       = (const float*)d_in[4];
    const float* bl       = (const float*)d_in[5];
    const int*   src      = (const int*)d_in[6];
    const int*   dst      = (const int*)d_in[7];
    float* out = (float*)d_out;

    const int N = 4096, IN = 512, H = 8192;
    const int E = in_sizes[6];

    char* ws = (char*)d_ws;
    size_t o = 0;
    auto alloc = [&](size_t bytes) -> char* {
        char* p = ws + o;
        o = (o + bytes + 255) & ~(size_t)255;
        return p;
    };
    short* W2t   = (short*)alloc((size_t)N * H * 2);     // 64 MB  W2^T bf16 [4096][8192]
    short* h1    = (short*)alloc((size_t)N * H * 2);     // 64 MB  conv1 out bf16 [4096][8192]
    short* x2s   = (short*)alloc((size_t)N * N * 2);     // 32 MB  (h1 W2)*inv_out bf16
    short* featb = (short*)alloc((size_t)N * IN * 2);    // 4 MB
    short* aggF  = (short*)alloc((size_t)N * IN * 2);    // 4 MB   A_hat X bf16
    short* W1t   = (short*)alloc((size_t)H * IN * 2);    // 8 MB   W1^T bf16 [8192][512]
    float* logitsP = (float*)alloc((size_t)8 * N * 16 * 4); // 2 MB partial logits
    float* deg_out = (float*)alloc(N * 4);
    float* deg_in  = (float*)alloc(N * 4);
    float* inv_out = (float*)alloc(N * 4);
    float* inv_in  = (float*)alloc(N * 4);
    float* rowsum  = (float*)alloc(N * 4);
    int*   cursor  = (int*)alloc(N * 4);
    int*   row_off = (int*)alloc((N + 1) * 4);
    int*   esrc    = (int*)alloc((size_t)E * 4);
    short* h2 = h1;   // alias: h1 dead after GEMM2, h2 written by agg2

    // graph prep
    k_zero <<<(N + 255) / 256, 256, 0, stream>>>(deg_out, deg_in, cursor, N);
    k_count<<<(E + 255) / 256, 256, 0, stream>>>(src, dst, deg_out, deg_in, E);
    k_inv  <<<(N + 255) / 256, 256, 0, stream>>>(deg_out, deg_in, inv_out, inv_in, N);
    k_scan <<<1, 1024, 0, stream>>>(deg_in, row_off);
    k_fill <<<(E + 255) / 256, 256, 0, stream>>>(src, dst, row_off, cursor, esrc, E);
    k_rowsum<<<N, 64, 0, stream>>>(row_off, esrc, inv_out, inv_in, rowsum);

    // operand conversion
    k_cvt_scale<<<(N * IN / 4 + 255) / 256, 256, 0, stream>>>(features, inv_out, featb,
                                                              N * IN / 4, IN / 4);
    k_tr2<<<dim3(H / 32, IN / 64), dim3(32, 8), 0, stream>>>(W1, W1t, IN, H);
    k_tr2<<<dim3(N / 32, H / 64), dim3(32, 8), 0, stream>>>(W2, W2t, H, N);

    // conv1: aggregate features first (F=512), then GEMM1 with rowsum*b1 epilogue
    agg_strip<0><<<dim3(1, N), 64, 0, stream>>>(featb, aggF, row_off, esrc, inv_in, IN);
    gemm8p<1><<<dim3(H / 256, N / 256), 512, 0, stream>>>(aggF, W1t, h1, b1, rowsum, N, H, IN);

    // conv2: project first, then aggregate (L2-striped: stripe = bid%8 = XCD)
    gemm8p<2><<<dim3(N / 256, N / 256), 512, 0, stream>>>(h1, W2t, x2s, nullptr, inv_out, N, N, H);
    agg_strip<1><<<dim3(N / 512, N), 64, 0, stream>>>(x2s, h2, row_off, esrc, inv_in, N);

    // head: split-K MFMA GEMM -> partials -> reduce+softmax
    k_headgemm<<<dim3(N / 256, 8), 256, 0, stream>>>(h2, Wl, logitsP);
    k_soft<<<N / 64, 64, 0, stream>>>(logitsP, bl, out);
}

// Round 10
// 433.084 us; speedup vs baseline: 1.1398x; 1.0025x over previous
//
#include <hip/hip_runtime.h>
#include <cstdint>
#include <cstddef>

// ---------------------------------------------------------------------------
// GCN forward:  softmax( (A_hat relu(A_hat (X W1 + b1) W2)) Wl + bl )
// conv1 reordered: aggregate features (F=512) first, GEMM1 epilogue adds
// rowsum*b1. conv2: project (8192->4096) then aggregate.
// GEMM: R6 pipeline (measured 260us, MfmaUtil 47.6%) - frozen.
// R10: k_tr3 (64x64 tiles, float4 in / short4 out, ~2x faster W2 transpose);
// agg_strip unroll x8 (2x memory-level parallelism vs x4).
// Head: split-K MFMA head-GEMM + reduce/softmax (R9).
// ---------------------------------------------------------------------------

using bf8   = __attribute__((ext_vector_type(8))) short;   // 8 bf16 (4 VGPR)
using s4    = __attribute__((ext_vector_type(4))) short;
using f32x4 = __attribute__((ext_vector_type(4))) float;

static __device__ __forceinline__ unsigned short f2bf(float f) {
    union { float f; uint32_t u; } v; v.f = f;
    uint32_t r = (v.u + 0x7FFFu + ((v.u >> 16) & 1u)) >> 16;   // RNE
    return (unsigned short)r;
}
static __device__ __forceinline__ float bf2f(unsigned short b) {
    union { uint32_t u; float f; } v; v.u = ((uint32_t)b) << 16;
    return v.f;
}

static __device__ __forceinline__ void gload16(const short* g, short* l) {
    __builtin_amdgcn_global_load_lds(
        (const __attribute__((address_space(1))) unsigned int*)g,
        (__attribute__((address_space(3))) unsigned int*)l,
        16, 0, 0);
}

// ---------------- prep kernels ----------------

__global__ void k_zero(float* a, float* b, int* c, int n) {
    int i = blockIdx.x * blockDim.x + threadIdx.x;
    if (i < n) { a[i] = 0.f; b[i] = 0.f; c[i] = 0; }
}

__global__ void k_count(const int* __restrict__ src, const int* __restrict__ dst,
                        float* deg_out, float* deg_in, int E) {
    int e = blockIdx.x * blockDim.x + threadIdx.x;
    if (e < E) {
        atomicAdd(&deg_out[src[e]], 1.f);
        atomicAdd(&deg_in[dst[e]], 1.f);
    }
}

__global__ void k_inv(const float* deg_out, const float* deg_in,
                      float* inv_out, float* inv_in, int n) {
    int i = blockIdx.x * blockDim.x + threadIdx.x;
    if (i < n) {
        inv_out[i] = rsqrtf(fmaxf(deg_out[i], 1.f));
        inv_in[i]  = rsqrtf(fmaxf(deg_in[i], 1.f));
    }
}

__global__ void k_scan(const float* __restrict__ deg_in, int* __restrict__ row_off) {
    __shared__ int part[1024];
    const int t = threadIdx.x;
    int v0 = (int)deg_in[t*4+0], v1 = (int)deg_in[t*4+1],
        v2 = (int)deg_in[t*4+2], v3 = (int)deg_in[t*4+3];
    part[t] = v0 + v1 + v2 + v3;
    __syncthreads();
    for (int off = 1; off < 1024; off <<= 1) {
        int x = (t >= off) ? part[t - off] : 0;
        __syncthreads();
        part[t] += x;
        __syncthreads();
    }
    int run = (t == 0) ? 0 : part[t-1];
    row_off[t*4+0] = run; run += v0;
    row_off[t*4+1] = run; run += v1;
    row_off[t*4+2] = run; run += v2;
    row_off[t*4+3] = run; run += v3;
    if (t == 1023) row_off[4096] = run;
}

__global__ void k_fill(const int* __restrict__ src, const int* __restrict__ dst,
                       const int* __restrict__ row_off, int* cursor,
                       int* __restrict__ esrc, int E) {
    int e = blockIdx.x * blockDim.x + threadIdx.x;
    if (e < E) {
        int d = dst[e];
        int p = atomicAdd(&cursor[d], 1);
        esrc[row_off[d] + p] = src[e];
    }
}

__global__ void k_rowsum(const int* __restrict__ row_off, const int* __restrict__ esrc,
                         const float* __restrict__ inv_out, const float* __restrict__ inv_in,
                         float* __restrict__ rowsum) {
    const int node = blockIdx.x, lane = threadIdx.x;
    const int beg = row_off[node], end = row_off[node + 1];
    float s = 0.f;
    for (int p = beg + lane; p < end; p += 64) s += inv_out[esrc[p]];
    #pragma unroll
    for (int off = 32; off; off >>= 1) s += __shfl_down(s, off, 64);
    if (lane == 0) rowsum[node] = s * inv_in[node];
}

__global__ void k_cvt_scale(const float* __restrict__ in, const float* __restrict__ sc,
                            short* __restrict__ out, int n4, int f4) {
    int i = blockIdx.x * blockDim.x + threadIdx.x;
    if (i < n4) {
        const float s = sc[i / f4];
        float4 v = reinterpret_cast<const float4*>(in)[i];
        s4 o;
        o[0] = (short)f2bf(v.x * s); o[1] = (short)f2bf(v.y * s);
        o[2] = (short)f2bf(v.z * s); o[3] = (short)f2bf(v.w * s);
        reinterpret_cast<s4*>(out)[i] = o;
    }
}

// fp32 [R][C] -> bf16 [C][R]; 64x64 tiles, 256 threads.
// Read: float4/thread, 4 passes (rows t>>4 + 16p). Write: short4/thread
// (4 consecutive r), 4 passes (cols t>>4 + 16p). LDS pad 65 -> write-phase
// reads are 2-way bank aliased (free, m136).
__global__ __launch_bounds__(256)
void k_tr3(const float* __restrict__ in, short* __restrict__ out, int R, int C) {
    __shared__ float tile[64][65];
    const int bc = blockIdx.x * 64, br = blockIdx.y * 64;
    const int t = threadIdx.x;
    const int rr = t >> 4, cq = (t & 15) * 4;
    #pragma unroll
    for (int p = 0; p < 4; ++p) {
        const int r = rr + p * 16;
        float4 v = *reinterpret_cast<const float4*>(&in[(size_t)(br + r) * C + bc + cq]);
        tile[r][cq + 0] = v.x; tile[r][cq + 1] = v.y;
        tile[r][cq + 2] = v.z; tile[r][cq + 3] = v.w;
    }
    __syncthreads();
    const int cc = t >> 4, rq = (t & 15) * 4;
    #pragma unroll
    for (int p = 0; p < 4; ++p) {
        const int c = cc + p * 16;
        s4 o;
        o[0] = (short)f2bf(tile[rq + 0][c]);
        o[1] = (short)f2bf(tile[rq + 1][c]);
        o[2] = (short)f2bf(tile[rq + 2][c]);
        o[3] = (short)f2bf(tile[rq + 3][c]);
        *reinterpret_cast<s4*>(&out[(size_t)(bc + c) * R + br + rq]) = o;
    }
}

// ---------------- bf16 MFMA GEMM, 4-phase counted-vmcnt pipeline (R6, frozen) ----------------
template<int EPI>
__global__ __launch_bounds__(512, 2)
void gemm8p(const short* __restrict__ A, const short* __restrict__ Bt,
            short* __restrict__ C,
            const float* __restrict__ bias, const float* __restrict__ rs,
            int M, int N, int K)
{
    constexpr int USZ  = 4096;            // shorts per 64-row x 64-short unit
    constexpr int BOFF = 4 * USZ;         // B region offset within buffer (16384)
    constexpr int BUF  = 8 * USZ;         // shorts per buffer (32768 = 64KB)
    __shared__ __align__(16) short lds[2 * BUF];   // 128 KB
    const int tid  = threadIdx.x;
    const int wid  = tid >> 6, lane = tid & 63;
    const int wm   = wid >> 2;            // 0..1  (M wave index)
    const int wn   = wid & 3;             // 0..3  (N wave index)
    const int fr   = lane & 15;
    const int kq   = lane >> 4;           // 0..3
    const int nt   = K >> 6;

    // bijective XCD-chunk swizzle (nwg % 8 == 0)
    const int gx  = gridDim.x;
    const int nwg = gx * gridDim.y;
    int bid = blockIdx.y * gx + blockIdx.x;
    bid = (bid & 7) * (nwg >> 3) + (bid >> 3);
    const int tm = (bid / gx) * 256;
    const int tn = (bid % gx) * 256;

    // ---- staging addressing ----
    const int srow = tid >> 3;
    const int scq  = tid & 7;
    const int scs  = scq ^ (srow & 7);    // pre-swizzled source chunk
    const short* gA = A  + (size_t)(tm + srow) * K + scs * 8;
    const short* gB = Bt + (size_t)(tn + srow) * K + scs * 8;
    short* const ldst = lds + tid * 8;

    // ---- fragment read offsets ----
    const int cx0 = (0 * 4 + kq) ^ (fr & 7);
    const int cx1 = (1 * 4 + kq) ^ (fr & 7);
    int aoff[8][2], boff[4][2];
    #pragma unroll
    for (int mi = 0; mi < 8; ++mi) {
        const int r = wm * 128 + mi * 16 + fr;
        aoff[mi][0] = r * 64 + cx0 * 8;
        aoff[mi][1] = r * 64 + cx1 * 8;
    }
    #pragma unroll
    for (int n = 0; n < 4; ++n) {
        const int r = wn * 64 + n * 16 + fr;
        boff[n][0] = BOFF + r * 64 + cx0 * 8;
        boff[n][1] = BOFF + r * 64 + cx1 * 8;
    }

    f32x4 acc[8][4];
    #pragma unroll
    for (int mi = 0; mi < 8; ++mi)
        #pragma unroll
        for (int n = 0; n < 4; ++n)
            acc[mi][n] = (f32x4){0.f, 0.f, 0.f, 0.f};

    // ---- prologue ----
    #pragma unroll
    for (int u = 0; u < 4; ++u) gload16(gA + (size_t)u * 64 * K, ldst + u * USZ);
    #pragma unroll
    for (int v = 0; v < 4; ++v) gload16(gB + (size_t)v * 64 * K, ldst + BOFF + v * USZ);
    #pragma unroll
    for (int u = 0; u < 4; ++u) gload16(gA + (size_t)u * 64 * K + 64, ldst + BUF + u * USZ);
    #pragma unroll
    for (int v = 0; v < 4; ++v) gload16(gB + (size_t)v * 64 * K + 64, ldst + BUF + BOFF + v * USZ);
    asm volatile("s_waitcnt vmcnt(8)" ::: "memory");
    __builtin_amdgcn_sched_barrier(0);
    __builtin_amdgcn_s_barrier();

    for (int t = 0; t < nt; ++t) {
        const int cc = (t & 1) * BUF;
        const bool pf = (t + 2 < nt);
        const size_t kf = (size_t)(t + 2) * 64;

        bf8 a03[4][2], a47[4][2], bg[4][2];

        // ---- P0 ----
        #pragma unroll
        for (int mi = 0; mi < 4; ++mi)
            #pragma unroll
            for (int s = 0; s < 2; ++s)
                a03[mi][s] = *reinterpret_cast<const bf8*>(lds + cc + aoff[mi][s]);
        #pragma unroll
        for (int n = 0; n < 2; ++n)
            #pragma unroll
            for (int s = 0; s < 2; ++s)
                bg[n][s] = *reinterpret_cast<const bf8*>(lds + cc + boff[n][s]);
        __builtin_amdgcn_s_barrier();
        asm volatile("s_waitcnt lgkmcnt(0)" ::: "memory");
        __builtin_amdgcn_sched_barrier(0);
        __builtin_amdgcn_s_setprio(1);
        #pragma unroll
        for (int mi = 0; mi < 4; ++mi)
            #pragma unroll
            for (int n = 0; n < 2; ++n)
                #pragma unroll
                for (int s = 0; s < 2; ++s)
                    acc[mi][n] = __builtin_amdgcn_mfma_f32_16x16x32_bf16(a03[mi][s], bg[n][s], acc[mi][n], 0, 0, 0);
        __builtin_amdgcn_s_setprio(0);
        __builtin_amdgcn_s_barrier();

        // ---- P1 ----
        #pragma unroll
        for (int n = 2; n < 4; ++n)
            #pragma unroll
            for (int s = 0; s < 2; ++s)
                bg[n][s] = *reinterpret_cast<const bf8*>(lds + cc + boff[n][s]);
        __builtin_amdgcn_s_barrier();
        asm volatile("s_waitcnt lgkmcnt(0)" ::: "memory");
        __builtin_amdgcn_sched_barrier(0);
        __builtin_amdgcn_s_setprio(1);
        #pragma unroll
        for (int mi = 0; mi < 4; ++mi)
            #pragma unroll
            for (int n = 2; n < 4; ++n)
                #pragma unroll
                for (int s = 0; s < 2; ++s)
                    acc[mi][n] = __builtin_amdgcn_mfma_f32_16x16x32_bf16(a03[mi][s], bg[n][s], acc[mi][n], 0, 0, 0);
        __builtin_amdgcn_s_setprio(0);
        __builtin_amdgcn_s_barrier();
        // B region dead => safe to overwrite.

        // ---- P2 ----
        #pragma unroll
        for (int mi = 0; mi < 4; ++mi)
            #pragma unroll
            for (int s = 0; s < 2; ++s)
                a47[mi][s] = *reinterpret_cast<const bf8*>(lds + cc + aoff[4 + mi][s]);
        if (pf) {
            #pragma unroll
            for (int v = 0; v < 4; ++v)
                gload16(gB + (size_t)v * 64 * K + kf, ldst + cc + BOFF + v * USZ);
        }
        __builtin_amdgcn_s_barrier();
        asm volatile("s_waitcnt lgkmcnt(0)" ::: "memory");
        __builtin_amdgcn_sched_barrier(0);
        __builtin_amdgcn_s_setprio(1);
        #pragma unroll
        for (int mi = 0; mi < 4; ++mi)
            #pragma unroll
            for (int n = 0; n < 2; ++n)
                #pragma unroll
                for (int s = 0; s < 2; ++s)
                    acc[4 + mi][n] = __builtin_amdgcn_mfma_f32_16x16x32_bf16(a47[mi][s], bg[n][s], acc[4 + mi][n], 0, 0, 0);
        __builtin_amdgcn_s_setprio(0);
        __builtin_amdgcn_s_barrier();
        // A region dead => safe to overwrite.

        // ---- P3 ----
        if (pf) {
            #pragma unroll
            for (int u = 0; u < 4; ++u)
                gload16(gA + (size_t)u * 64 * K + kf, ldst + cc + u * USZ);
        }
        __builtin_amdgcn_s_setprio(1);
        #pragma unroll
        for (int mi = 0; mi < 4; ++mi)
            #pragma unroll
            for (int n = 2; n < 4; ++n)
                #pragma unroll
                for (int s = 0; s < 2; ++s)
                    acc[4 + mi][n] = __builtin_amdgcn_mfma_f32_16x16x32_bf16(a47[mi][s], bg[n][s], acc[4 + mi][n], 0, 0, 0);
        __builtin_amdgcn_s_setprio(0);
        if (pf) {
            asm volatile("s_waitcnt vmcnt(8)" ::: "memory");
        } else if (t + 2 == nt) {
            asm volatile("s_waitcnt vmcnt(0)" ::: "memory");
        }
        __builtin_amdgcn_sched_barrier(0);
        __builtin_amdgcn_s_barrier();
    }

    // ---- epilogue ----
    const int rb = kq * 4;
    #pragma unroll
    for (int mi = 0; mi < 8; ++mi) {
        #pragma unroll
        for (int n = 0; n < 4; ++n) {
            const int col = tn + wn * 64 + n * 16 + fr;
            const float bcol = (EPI == 1) ? bias[col] : 0.f;
            #pragma unroll
            for (int j = 0; j < 4; ++j) {
                const int row = tm + wm * 128 + mi * 16 + rb + j;
                float v = acc[mi][n][j];
                if (EPI == 1) v += rs[row] * bcol;
                else          v *= rs[row];
                C[(size_t)row * N + col] = (short)f2bf(v);
            }
        }
    }
}

// ---------------- CSR aggregation, L2-striped, x8 unrolled ----------------
template<int RELU>
__global__ __launch_bounds__(64)
void agg_strip(const short* __restrict__ X, short* __restrict__ Y,
               const int* __restrict__ row_off, const int* __restrict__ esrc,
               const float* __restrict__ inv_in, int F)
{
    const int node = blockIdx.y;
    const int c0 = blockIdx.x * 512 + threadIdx.x * 8;
    float acc[8];
    #pragma unroll
    for (int j = 0; j < 8; ++j) acc[j] = 0.f;

    const int beg = row_off[node], end = row_off[node + 1];
    int p = beg;
    for (; p + 7 < end; p += 8) {
        bf8 x[8];
        #pragma unroll
        for (int u = 0; u < 8; ++u)
            x[u] = *reinterpret_cast<const bf8*>(X + (size_t)esrc[p + u] * F + c0);
        #pragma unroll
        for (int u = 0; u < 8; ++u)
            #pragma unroll
            for (int j = 0; j < 8; ++j)
                acc[j] += bf2f((unsigned short)x[u][j]);
    }
    for (; p < end; ++p) {
        bf8 x0 = *reinterpret_cast<const bf8*>(X + (size_t)esrc[p] * F + c0);
        #pragma unroll
        for (int j = 0; j < 8; ++j) acc[j] += bf2f((unsigned short)x0[j]);
    }
    const float sc = inv_in[node];
    bf8 o;
    #pragma unroll
    for (int j = 0; j < 8; ++j) {
        float v = acc[j] * sc;
        if (RELU) v = fmaxf(v, 0.f);
        o[j] = (short)f2bf(v);
    }
    *reinterpret_cast<bf8*>(Y + (size_t)node * F + c0) = o;
}

// ---------------- head-GEMM + softmax (R9) ----------------
__global__ __launch_bounds__(256)
void k_headgemm(const short* __restrict__ H, const float* __restrict__ Wl,
                float* __restrict__ logitsP)
{
    constexpr int RS = 520;
    __shared__ __align__(16) short ldsB[16 * RS];
    const int tid = threadIdx.x;
    const int m0  = blockIdx.x * 256;
    const int k0  = blockIdx.y * 512;
    const int wid = tid >> 6, lane = tid & 63;
    const int fr  = lane & 15;
    const int kq  = lane >> 4;

    {
        const int c = tid & 15, kk = tid >> 4;
        #pragma unroll
        for (int j = 0; j < 32; ++j) {
            const int k = kk * 32 + j;
            ldsB[c * RS + k] = (short)f2bf(Wl[(size_t)(k0 + k) * 16 + c]);
        }
    }
    __syncthreads();

    const int rb0 = m0 + wid * 64;
    f32x4 acc[4];
    #pragma unroll
    for (int mi = 0; mi < 4; ++mi) acc[mi] = (f32x4){0.f, 0.f, 0.f, 0.f};

    #pragma unroll 4
    for (int s = 0; s < 16; ++s) {
        const bf8 b = *reinterpret_cast<const bf8*>(ldsB + fr * RS + s * 32 + kq * 8);
        #pragma unroll
        for (int mi = 0; mi < 4; ++mi) {
            const bf8 a = *reinterpret_cast<const bf8*>(
                H + (size_t)(rb0 + mi * 16 + fr) * 4096 + k0 + s * 32 + kq * 8);
            acc[mi] = __builtin_amdgcn_mfma_f32_16x16x32_bf16(a, b, acc[mi], 0, 0, 0);
        }
    }

    float* outP = logitsP + (size_t)blockIdx.y * 4096 * 16;
    #pragma unroll
    for (int mi = 0; mi < 4; ++mi)
        #pragma unroll
        for (int j = 0; j < 4; ++j)
            outP[(size_t)(rb0 + mi * 16 + kq * 4 + j) * 16 + fr] = acc[mi][j];
}

__global__ __launch_bounds__(64)
void k_soft(const float* __restrict__ logitsP, const float* __restrict__ bl,
            float* __restrict__ out)
{
    const int node = blockIdx.x * 64 + threadIdx.x;
    float l[16];
    #pragma unroll
    for (int c = 0; c < 16; ++c) l[c] = bl[c];
    for (int p = 0; p < 8; ++p) {
        const float4* lp = reinterpret_cast<const float4*>(
            logitsP + ((size_t)p * 4096 + node) * 16);
        #pragma unroll
        for (int q = 0; q < 4; ++q) {
            float4 v = lp[q];
            l[q*4+0] += v.x; l[q*4+1] += v.y; l[q*4+2] += v.z; l[q*4+3] += v.w;
        }
    }
    float mx = l[0];
    #pragma unroll
    for (int c = 1; c < 16; ++c) mx = fmaxf(mx, l[c]);
    float s = 0.f;
    #pragma unroll
    for (int c = 0; c < 16; ++c) { l[c] = expf(l[c] - mx); s += l[c]; }
    const float inv = 1.f / s;
    float4* o = reinterpret_cast<float4*>(out + (size_t)node * 16);
    #pragma unroll
    for (int q = 0; q < 4; ++q)
        o[q] = make_float4(l[q*4+0]*inv, l[q*4+1]*inv, l[q*4+2]*inv, l[q*4+3]*inv);
}

// ---------------- launch ----------------

extern "C" void kernel_launch(void* const* d_in, const int* in_sizes, int n_in,
                              void* d_out, int out_size, void* d_ws, size_t ws_size,
                              hipStream_t stream)
{
    const float* features = (const float*)d_in[0];
    const float* W1       = (const float*)d_in[1];
    const float* b1       = (const float*)d_in[2];
    const float* W2       = (const float*)d_in[3];
    const float* Wl       = (const float*)d_in[4];
    const float* bl       = (const float*)d_in[5];
    const int*   src      = (const int*)d_in[6];
    const int*   dst      = (const int*)d_in[7];
    float* out = (float*)d_out;

    const int N = 4096, IN = 512, H = 8192;
    const int E = in_sizes[6];

    char* ws = (char*)d_ws;
    size_t o = 0;
    auto alloc = [&](size_t bytes) -> char* {
        char* p = ws + o;
        o = (o + bytes + 255) & ~(size_t)255;
        return p;
    };
    short* W2t   = (short*)alloc((size_t)N * H * 2);     // 64 MB  W2^T bf16 [4096][8192]
    short* h1    = (short*)alloc((size_t)N * H * 2);     // 64 MB  conv1 out bf16 [4096][8192]
    short* x2s   = (short*)alloc((size_t)N * N * 2);     // 32 MB  (h1 W2)*inv_out bf16
    short* featb = (short*)alloc((size_t)N * IN * 2);    // 4 MB
    short* aggF  = (short*)alloc((size_t)N * IN * 2);    // 4 MB   A_hat X bf16
    short* W1t   = (short*)alloc((size_t)H * IN * 2);    // 8 MB   W1^T bf16 [8192][512]
    float* logitsP = (float*)alloc((size_t)8 * N * 16 * 4); // 2 MB partial logits
    float* deg_out = (float*)alloc(N * 4);
    float* deg_in  = (float*)alloc(N * 4);
    float* inv_out = (float*)alloc(N * 4);
    float* inv_in  = (float*)alloc(N * 4);
    float* rowsum  = (float*)alloc(N * 4);
    int*   cursor  = (int*)alloc(N * 4);
    int*   row_off = (int*)alloc((N + 1) * 4);
    int*   esrc    = (int*)alloc((size_t)E * 4);
    short* h2 = h1;   // alias: h1 dead after GEMM2, h2 written by agg2

    // graph prep
    k_zero <<<(N + 255) / 256, 256, 0, stream>>>(deg_out, deg_in, cursor, N);
    k_count<<<(E + 255) / 256, 256, 0, stream>>>(src, dst, deg_out, deg_in, E);
    k_inv  <<<(N + 255) / 256, 256, 0, stream>>>(deg_out, deg_in, inv_out, inv_in, N);
    k_scan <<<1, 1024, 0, stream>>>(deg_in, row_off);
    k_fill <<<(E + 255) / 256, 256, 0, stream>>>(src, dst, row_off, cursor, esrc, E);
    k_rowsum<<<N, 64, 0, stream>>>(row_off, esrc, inv_out, inv_in, rowsum);

    // operand conversion
    k_cvt_scale<<<(N * IN / 4 + 255) / 256, 256, 0, stream>>>(features, inv_out, featb,
                                                              N * IN / 4, IN / 4);
    k_tr3<<<dim3(H / 64, IN / 64), 256, 0, stream>>>(W1, W1t, IN, H);
    k_tr3<<<dim3(N / 64, H / 64), 256, 0, stream>>>(W2, W2t, H, N);

    // conv1: aggregate features first (F=512), then GEMM1 with rowsum*b1 epilogue
    agg_strip<0><<<dim3(1, N), 64, 0, stream>>>(featb, aggF, row_off, esrc, inv_in, IN);
    gemm8p<1><<<dim3(H / 256, N / 256), 512, 0, stream>>>(aggF, W1t, h1, b1, rowsum, N, H, IN);

    // conv2: project first, then aggregate (L2-striped: stripe = bid%8 = XCD)
    gemm8p<2><<<dim3(N / 256, N / 256), 512, 0, stream>>>(h1, W2t, x2s, nullptr, inv_out, N, N, H);
    agg_strip<1><<<dim3(N / 512, N), 64, 0, stream>>>(x2s, h2, row_off, esrc, inv_in, N);

    // head: split-K MFMA GEMM -> partials -> reduce+softmax
    k_headgemm<<<dim3(N / 256, 8), 256, 0, stream>>>(h2, Wl, logitsP);
    k_soft<<<N / 64, 64, 0, stream>>>(logitsP, bl, out);
}

// Round 11
// 432.865 us; speedup vs baseline: 1.1404x; 1.0005x over previous
//
#include <hip/hip_runtime.h>
#include <cstdint>
#include <cstddef>

// ---------------------------------------------------------------------------
// GCN forward:  softmax( (A_hat relu(A_hat (X W1 + b1) W2)) Wl + bl )
// conv1 reordered: aggregate features (F=512) first, GEMM1 epilogue adds
// rowsum*b1. conv2: project (8192->4096) then aggregate.
// GEMM (R11): R6 4-phase counted-vmcnt pipeline WITHOUT per-phase
// sched_barrier(0) pins: per rule #18, hipcc hoists register-only MFMAs
// past the asm lgkmcnt(0); each MFMA is still guarded by compiler-inserted
// COUNTED lgkm waits on its own operands, so early-arriving fragments start
// MFMA while the remaining LDS reads are serviced (the m201 overlap
// mechanism). Memory ops still cannot cross the "memory"-clobbered asm.
// ---------------------------------------------------------------------------

using bf8   = __attribute__((ext_vector_type(8))) short;   // 8 bf16 (4 VGPR)
using s4    = __attribute__((ext_vector_type(4))) short;
using f32x4 = __attribute__((ext_vector_type(4))) float;

static __device__ __forceinline__ unsigned short f2bf(float f) {
    union { float f; uint32_t u; } v; v.f = f;
    uint32_t r = (v.u + 0x7FFFu + ((v.u >> 16) & 1u)) >> 16;   // RNE
    return (unsigned short)r;
}
static __device__ __forceinline__ float bf2f(unsigned short b) {
    union { uint32_t u; float f; } v; v.u = ((uint32_t)b) << 16;
    return v.f;
}

static __device__ __forceinline__ void gload16(const short* g, short* l) {
    __builtin_amdgcn_global_load_lds(
        (const __attribute__((address_space(1))) unsigned int*)g,
        (__attribute__((address_space(3))) unsigned int*)l,
        16, 0, 0);
}

// ---------------- prep kernels ----------------

__global__ void k_zero(float* a, float* b, int* c, int n) {
    int i = blockIdx.x * blockDim.x + threadIdx.x;
    if (i < n) { a[i] = 0.f; b[i] = 0.f; c[i] = 0; }
}

__global__ void k_count(const int* __restrict__ src, const int* __restrict__ dst,
                        float* deg_out, float* deg_in, int E) {
    int e = blockIdx.x * blockDim.x + threadIdx.x;
    if (e < E) {
        atomicAdd(&deg_out[src[e]], 1.f);
        atomicAdd(&deg_in[dst[e]], 1.f);
    }
}

__global__ void k_inv(const float* deg_out, const float* deg_in,
                      float* inv_out, float* inv_in, int n) {
    int i = blockIdx.x * blockDim.x + threadIdx.x;
    if (i < n) {
        inv_out[i] = rsqrtf(fmaxf(deg_out[i], 1.f));
        inv_in[i]  = rsqrtf(fmaxf(deg_in[i], 1.f));
    }
}

__global__ void k_scan(const float* __restrict__ deg_in, int* __restrict__ row_off) {
    __shared__ int part[1024];
    const int t = threadIdx.x;
    int v0 = (int)deg_in[t*4+0], v1 = (int)deg_in[t*4+1],
        v2 = (int)deg_in[t*4+2], v3 = (int)deg_in[t*4+3];
    part[t] = v0 + v1 + v2 + v3;
    __syncthreads();
    for (int off = 1; off < 1024; off <<= 1) {
        int x = (t >= off) ? part[t - off] : 0;
        __syncthreads();
        part[t] += x;
        __syncthreads();
    }
    int run = (t == 0) ? 0 : part[t-1];
    row_off[t*4+0] = run; run += v0;
    row_off[t*4+1] = run; run += v1;
    row_off[t*4+2] = run; run += v2;
    row_off[t*4+3] = run; run += v3;
    if (t == 1023) row_off[4096] = run;
}

__global__ void k_fill(const int* __restrict__ src, const int* __restrict__ dst,
                       const int* __restrict__ row_off, int* cursor,
                       int* __restrict__ esrc, int E) {
    int e = blockIdx.x * blockDim.x + threadIdx.x;
    if (e < E) {
        int d = dst[e];
        int p = atomicAdd(&cursor[d], 1);
        esrc[row_off[d] + p] = src[e];
    }
}

__global__ void k_rowsum(const int* __restrict__ row_off, const int* __restrict__ esrc,
                         const float* __restrict__ inv_out, const float* __restrict__ inv_in,
                         float* __restrict__ rowsum) {
    const int node = blockIdx.x, lane = threadIdx.x;
    const int beg = row_off[node], end = row_off[node + 1];
    float s = 0.f;
    for (int p = beg + lane; p < end; p += 64) s += inv_out[esrc[p]];
    #pragma unroll
    for (int off = 32; off; off >>= 1) s += __shfl_down(s, off, 64);
    if (lane == 0) rowsum[node] = s * inv_in[node];
}

__global__ void k_cvt_scale(const float* __restrict__ in, const float* __restrict__ sc,
                            short* __restrict__ out, int n4, int f4) {
    int i = blockIdx.x * blockDim.x + threadIdx.x;
    if (i < n4) {
        const float s = sc[i / f4];
        float4 v = reinterpret_cast<const float4*>(in)[i];
        s4 o;
        o[0] = (short)f2bf(v.x * s); o[1] = (short)f2bf(v.y * s);
        o[2] = (short)f2bf(v.z * s); o[3] = (short)f2bf(v.w * s);
        reinterpret_cast<s4*>(out)[i] = o;
    }
}

// fp32 [R][C] -> bf16 [C][R]; 64x64 tiles, 256 threads.
__global__ __launch_bounds__(256)
void k_tr3(const float* __restrict__ in, short* __restrict__ out, int R, int C) {
    __shared__ float tile[64][65];
    const int bc = blockIdx.x * 64, br = blockIdx.y * 64;
    const int t = threadIdx.x;
    const int rr = t >> 4, cq = (t & 15) * 4;
    #pragma unroll
    for (int p = 0; p < 4; ++p) {
        const int r = rr + p * 16;
        float4 v = *reinterpret_cast<const float4*>(&in[(size_t)(br + r) * C + bc + cq]);
        tile[r][cq + 0] = v.x; tile[r][cq + 1] = v.y;
        tile[r][cq + 2] = v.z; tile[r][cq + 3] = v.w;
    }
    __syncthreads();
    const int cc = t >> 4, rq = (t & 15) * 4;
    #pragma unroll
    for (int p = 0; p < 4; ++p) {
        const int c = cc + p * 16;
        s4 o;
        o[0] = (short)f2bf(tile[rq + 0][c]);
        o[1] = (short)f2bf(tile[rq + 1][c]);
        o[2] = (short)f2bf(tile[rq + 2][c]);
        o[3] = (short)f2bf(tile[rq + 3][c]);
        *reinterpret_cast<s4*>(&out[(size_t)(bc + c) * R + br + rq]) = o;
    }
}

// ---------------- bf16 MFMA GEMM, 4-phase counted-vmcnt pipeline ----------------
// R6 structure; R11: NO per-phase sched_barrier(0) -> compiler may hoist
// register-only MFMAs past the asm lgkmcnt(0), overlapping LDS-read tail
// with MFMA via its own counted operand waits (rule #18 mechanism).
template<int EPI>
__global__ __launch_bounds__(512, 2)
void gemm8p(const short* __restrict__ A, const short* __restrict__ Bt,
            short* __restrict__ C,
            const float* __restrict__ bias, const float* __restrict__ rs,
            int M, int N, int K)
{
    constexpr int USZ  = 4096;            // shorts per 64-row x 64-short unit
    constexpr int BOFF = 4 * USZ;         // B region offset within buffer (16384)
    constexpr int BUF  = 8 * USZ;         // shorts per buffer (32768 = 64KB)
    __shared__ __align__(16) short lds[2 * BUF];   // 128 KB
    const int tid  = threadIdx.x;
    const int wid  = tid >> 6, lane = tid & 63;
    const int wm   = wid >> 2;            // 0..1  (M wave index)
    const int wn   = wid & 3;             // 0..3  (N wave index)
    const int fr   = lane & 15;
    const int kq   = lane >> 4;           // 0..3
    const int nt   = K >> 6;

    // bijective XCD-chunk swizzle (nwg % 8 == 0)
    const int gx  = gridDim.x;
    const int nwg = gx * gridDim.y;
    int bid = blockIdx.y * gx + blockIdx.x;
    bid = (bid & 7) * (nwg >> 3) + (bid >> 3);
    const int tm = (bid / gx) * 256;
    const int tn = (bid % gx) * 256;

    // ---- staging addressing ----
    const int srow = tid >> 3;
    const int scq  = tid & 7;
    const int scs  = scq ^ (srow & 7);    // pre-swizzled source chunk
    const short* gA = A  + (size_t)(tm + srow) * K + scs * 8;
    const short* gB = Bt + (size_t)(tn + srow) * K + scs * 8;
    short* const ldst = lds + tid * 8;

    // ---- fragment read offsets ----
    const int cx0 = (0 * 4 + kq) ^ (fr & 7);
    const int cx1 = (1 * 4 + kq) ^ (fr & 7);
    int aoff[8][2], boff[4][2];
    #pragma unroll
    for (int mi = 0; mi < 8; ++mi) {
        const int r = wm * 128 + mi * 16 + fr;
        aoff[mi][0] = r * 64 + cx0 * 8;
        aoff[mi][1] = r * 64 + cx1 * 8;
    }
    #pragma unroll
    for (int n = 0; n < 4; ++n) {
        const int r = wn * 64 + n * 16 + fr;
        boff[n][0] = BOFF + r * 64 + cx0 * 8;
        boff[n][1] = BOFF + r * 64 + cx1 * 8;
    }

    f32x4 acc[8][4];
    #pragma unroll
    for (int mi = 0; mi < 8; ++mi)
        #pragma unroll
        for (int n = 0; n < 4; ++n)
            acc[mi][n] = (f32x4){0.f, 0.f, 0.f, 0.f};

    // ---- prologue: stage tile 0 -> buf0, tile 1 -> buf1; wait tile 0 ----
    #pragma unroll
    for (int u = 0; u < 4; ++u) gload16(gA + (size_t)u * 64 * K, ldst + u * USZ);
    #pragma unroll
    for (int v = 0; v < 4; ++v) gload16(gB + (size_t)v * 64 * K, ldst + BOFF + v * USZ);
    #pragma unroll
    for (int u = 0; u < 4; ++u) gload16(gA + (size_t)u * 64 * K + 64, ldst + BUF + u * USZ);
    #pragma unroll
    for (int v = 0; v < 4; ++v) gload16(gB + (size_t)v * 64 * K + 64, ldst + BUF + BOFF + v * USZ);
    asm volatile("s_waitcnt vmcnt(8)" ::: "memory");
    __builtin_amdgcn_sched_barrier(0);
    __builtin_amdgcn_s_barrier();

    for (int t = 0; t < nt; ++t) {
        const int cc = (t & 1) * BUF;
        const bool pf = (t + 2 < nt);
        const size_t kf = (size_t)(t + 2) * 64;

        bf8 a03[4][2], a47[4][2], bg[4][2];

        // ---- P0: read A m0-3 (8) + B n0-1 (4); 16 MFMA (m0-3 x n0-1) ----
        #pragma unroll
        for (int mi = 0; mi < 4; ++mi)
            #pragma unroll
            for (int s = 0; s < 2; ++s)
                a03[mi][s] = *reinterpret_cast<const bf8*>(lds + cc + aoff[mi][s]);
        #pragma unroll
        for (int n = 0; n < 2; ++n)
            #pragma unroll
            for (int s = 0; s < 2; ++s)
                bg[n][s] = *reinterpret_cast<const bf8*>(lds + cc + boff[n][s]);
        __builtin_amdgcn_s_barrier();
        asm volatile("s_waitcnt lgkmcnt(0)" ::: "memory");
        __builtin_amdgcn_s_setprio(1);
        #pragma unroll
        for (int mi = 0; mi < 4; ++mi)
            #pragma unroll
            for (int n = 0; n < 2; ++n)
                #pragma unroll
                for (int s = 0; s < 2; ++s)
                    acc[mi][n] = __builtin_amdgcn_mfma_f32_16x16x32_bf16(a03[mi][s], bg[n][s], acc[mi][n], 0, 0, 0);
        __builtin_amdgcn_s_setprio(0);
        __builtin_amdgcn_s_barrier();

        // ---- P1: read B n2-3 (4); 16 MFMA (m0-3 x n2-3) ----
        #pragma unroll
        for (int n = 2; n < 4; ++n)
            #pragma unroll
            for (int s = 0; s < 2; ++s)
                bg[n][s] = *reinterpret_cast<const bf8*>(lds + cc + boff[n][s]);
        __builtin_amdgcn_s_barrier();
        asm volatile("s_waitcnt lgkmcnt(0)" ::: "memory");
        __builtin_amdgcn_s_setprio(1);
        #pragma unroll
        for (int mi = 0; mi < 4; ++mi)
            #pragma unroll
            for (int n = 2; n < 4; ++n)
                #pragma unroll
                for (int s = 0; s < 2; ++s)
                    acc[mi][n] = __builtin_amdgcn_mfma_f32_16x16x32_bf16(a03[mi][s], bg[n][s], acc[mi][n], 0, 0, 0);
        __builtin_amdgcn_s_setprio(0);
        __builtin_amdgcn_s_barrier();
        // B region of tile t dead (frags reg-cached, reads drained) => overwritable.

        // ---- P2: read A m4-7 (8); stage B(t+2) into cc; 16 MFMA (m4-7 x n0-1) ----
        #pragma unroll
        for (int mi = 0; mi < 4; ++mi)
            #pragma unroll
            for (int s = 0; s < 2; ++s)
                a47[mi][s] = *reinterpret_cast<const bf8*>(lds + cc + aoff[4 + mi][s]);
        if (pf) {
            #pragma unroll
            for (int v = 0; v < 4; ++v)
                gload16(gB + (size_t)v * 64 * K + kf, ldst + cc + BOFF + v * USZ);
        }
        __builtin_amdgcn_s_barrier();
        asm volatile("s_waitcnt lgkmcnt(0)" ::: "memory");
        __builtin_amdgcn_s_setprio(1);
        #pragma unroll
        for (int mi = 0; mi < 4; ++mi)
            #pragma unroll
            for (int n = 0; n < 2; ++n)
                #pragma unroll
                for (int s = 0; s < 2; ++s)
                    acc[4 + mi][n] = __builtin_amdgcn_mfma_f32_16x16x32_bf16(a47[mi][s], bg[n][s], acc[4 + mi][n], 0, 0, 0);
        __builtin_amdgcn_s_setprio(0);
        __builtin_amdgcn_s_barrier();
        // A region of tile t dead => overwritable.

        // ---- P3: stage A(t+2) into cc; 16 MFMA (m4-7 x n2-3); counted wait ----
        if (pf) {
            #pragma unroll
            for (int u = 0; u < 4; ++u)
                gload16(gA + (size_t)u * 64 * K + kf, ldst + cc + u * USZ);
        }
        __builtin_amdgcn_s_setprio(1);
        #pragma unroll
        for (int mi = 0; mi < 4; ++mi)
            #pragma unroll
            for (int n = 2; n < 4; ++n)
                #pragma unroll
                for (int s = 0; s < 2; ++s)
                    acc[4 + mi][n] = __builtin_amdgcn_mfma_f32_16x16x32_bf16(a47[mi][s], bg[n][s], acc[4 + mi][n], 0, 0, 0);
        __builtin_amdgcn_s_setprio(0);
        if (pf) {
            asm volatile("s_waitcnt vmcnt(8)" ::: "memory");   // t+1 landed; t+2 in flight
        } else if (t + 2 == nt) {
            asm volatile("s_waitcnt vmcnt(0)" ::: "memory");   // last prefetched tile
        }
        __builtin_amdgcn_s_barrier();
    }

    // ---- epilogue: C/D layout col = lane&15, row = (lane>>4)*4 + reg ----
    const int rb = kq * 4;
    #pragma unroll
    for (int mi = 0; mi < 8; ++mi) {
        #pragma unroll
        for (int n = 0; n < 4; ++n) {
            const int col = tn + wn * 64 + n * 16 + fr;
            const float bcol = (EPI == 1) ? bias[col] : 0.f;
            #pragma unroll
            for (int j = 0; j < 4; ++j) {
                const int row = tm + wm * 128 + mi * 16 + rb + j;
                float v = acc[mi][n][j];
                if (EPI == 1) v += rs[row] * bcol;
                else          v *= rs[row];
                C[(size_t)row * N + col] = (short)f2bf(v);
            }
        }
    }
}

// ---------------- CSR aggregation, L2-striped, x8 unrolled ----------------
template<int RELU>
__global__ __launch_bounds__(64)
void agg_strip(const short* __restrict__ X, short* __restrict__ Y,
               const int* __restrict__ row_off, const int* __restrict__ esrc,
               const float* __restrict__ inv_in, int F)
{
    const int node = blockIdx.y;
    const int c0 = blockIdx.x * 512 + threadIdx.x * 8;
    float acc[8];
    #pragma unroll
    for (int j = 0; j < 8; ++j) acc[j] = 0.f;

    const int beg = row_off[node], end = row_off[node + 1];
    int p = beg;
    for (; p + 7 < end; p += 8) {
        bf8 x[8];
        #pragma unroll
        for (int u = 0; u < 8; ++u)
            x[u] = *reinterpret_cast<const bf8*>(X + (size_t)esrc[p + u] * F + c0);
        #pragma unroll
        for (int u = 0; u < 8; ++u)
            #pragma unroll
            for (int j = 0; j < 8; ++j)
                acc[j] += bf2f((unsigned short)x[u][j]);
    }
    for (; p < end; ++p) {
        bf8 x0 = *reinterpret_cast<const bf8*>(X + (size_t)esrc[p] * F + c0);
        #pragma unroll
        for (int j = 0; j < 8; ++j) acc[j] += bf2f((unsigned short)x0[j]);
    }
    const float sc = inv_in[node];
    bf8 o;
    #pragma unroll
    for (int j = 0; j < 8; ++j) {
        float v = acc[j] * sc;
        if (RELU) v = fmaxf(v, 0.f);
        o[j] = (short)f2bf(v);
    }
    *reinterpret_cast<bf8*>(Y + (size_t)node * F + c0) = o;
}

// ---------------- head-GEMM + softmax (R9) ----------------
__global__ __launch_bounds__(256)
void k_headgemm(const short* __restrict__ H, const float* __restrict__ Wl,
                float* __restrict__ logitsP)
{
    constexpr int RS = 520;
    __shared__ __align__(16) short ldsB[16 * RS];
    const int tid = threadIdx.x;
    const int m0  = blockIdx.x * 256;
    const int k0  = blockIdx.y * 512;
    const int wid = tid >> 6, lane = tid & 63;
    const int fr  = lane & 15;
    const int kq  = lane >> 4;

    {
        const int c = tid & 15, kk = tid >> 4;
        #pragma unroll
        for (int j = 0; j < 32; ++j) {
            const int k = kk * 32 + j;
            ldsB[c * RS + k] = (short)f2bf(Wl[(size_t)(k0 + k) * 16 + c]);
        }
    }
    __syncthreads();

    const int rb0 = m0 + wid * 64;
    f32x4 acc[4];
    #pragma unroll
    for (int mi = 0; mi < 4; ++mi) acc[mi] = (f32x4){0.f, 0.f, 0.f, 0.f};

    #pragma unroll 4
    for (int s = 0; s < 16; ++s) {
        const bf8 b = *reinterpret_cast<const bf8*>(ldsB + fr * RS + s * 32 + kq * 8);
        #pragma unroll
        for (int mi = 0; mi < 4; ++mi) {
            const bf8 a = *reinterpret_cast<const bf8*>(
                H + (size_t)(rb0 + mi * 16 + fr) * 4096 + k0 + s * 32 + kq * 8);
            acc[mi] = __builtin_amdgcn_mfma_f32_16x16x32_bf16(a, b, acc[mi], 0, 0, 0);
        }
    }

    float* outP = logitsP + (size_t)blockIdx.y * 4096 * 16;
    #pragma unroll
    for (int mi = 0; mi < 4; ++mi)
        #pragma unroll
        for (int j = 0; j < 4; ++j)
            outP[(size_t)(rb0 + mi * 16 + kq * 4 + j) * 16 + fr] = acc[mi][j];
}

__global__ __launch_bounds__(64)
void k_soft(const float* __restrict__ logitsP, const float* __restrict__ bl,
            float* __restrict__ out)
{
    const int node = blockIdx.x * 64 + threadIdx.x;
    float l[16];
    #pragma unroll
    for (int c = 0; c < 16; ++c) l[c] = bl[c];
    for (int p = 0; p < 8; ++p) {
        const float4* lp = reinterpret_cast<const float4*>(
            logitsP + ((size_t)p * 4096 + node) * 16);
        #pragma unroll
        for (int q = 0; q < 4; ++q) {
            float4 v = lp[q];
            l[q*4+0] += v.x; l[q*4+1] += v.y; l[q*4+2] += v.z; l[q*4+3] += v.w;
        }
    }
    float mx = l[0];
    #pragma unroll
    for (int c = 1; c < 16; ++c) mx = fmaxf(mx, l[c]);
    float s = 0.f;
    #pragma unroll
    for (int c = 0; c < 16; ++c) { l[c] = expf(l[c] - mx); s += l[c]; }
    const float inv = 1.f / s;
    float4* o = reinterpret_cast<float4*>(out + (size_t)node * 16);
    #pragma unroll
    for (int q = 0; q < 4; ++q)
        o[q] = make_float4(l[q*4+0]*inv, l[q*4+1]*inv, l[q*4+2]*inv, l[q*4+3]*inv);
}

// ---------------- launch ----------------

extern "C" void kernel_launch(void* const* d_in, const int* in_sizes, int n_in,
                              void* d_out, int out_size, void* d_ws, size_t ws_size,
                              hipStream_t stream)
{
    const float* features = (const float*)d_in[0];
    const float* W1       = (const float*)d_in[1];
    const float* b1       = (const float*)d_in[2];
    const float* W2       = (const float*)d_in[3];
    const float* Wl       = (const float*)d_in[4];
    const float* bl       = (const float*)d_in[5];
    const int*   src      = (const int*)d_in[6];
    const int*   dst      = (const int*)d_in[7];
    float* out = (float*)d_out;

    const int N = 4096, IN = 512, H = 8192;
    const int E = in_sizes[6];

    char* ws = (char*)d_ws;
    size_t o = 0;
    auto alloc = [&](size_t bytes) -> char* {
        char* p = ws + o;
        o = (o + bytes + 255) & ~(size_t)255;
        return p;
    };
    short* W2t   = (short*)alloc((size_t)N * H * 2);     // 64 MB  W2^T bf16 [4096][8192]
    short* h1    = (short*)alloc((size_t)N * H * 2);     // 64 MB  conv1 out bf16 [4096][8192]
    short* x2s   = (short*)alloc((size_t)N * N * 2);     // 32 MB  (h1 W2)*inv_out bf16
    short* featb = (short*)alloc((size_t)N * IN * 2);    // 4 MB
    short* aggF  = (short*)alloc((size_t)N * IN * 2);    // 4 MB   A_hat X bf16
    short* W1t   = (short*)alloc((size_t)H * IN * 2);    // 8 MB   W1^T bf16 [8192][512]
    float* logitsP = (float*)alloc((size_t)8 * N * 16 * 4); // 2 MB partial logits
    float* deg_out = (float*)alloc(N * 4);
    float* deg_in  = (float*)alloc(N * 4);
    float* inv_out = (float*)alloc(N * 4);
    float* inv_in  = (float*)alloc(N * 4);
    float* rowsum  = (float*)alloc(N * 4);
    int*   cursor  = (int*)alloc(N * 4);
    int*   row_off = (int*)alloc((N + 1) * 4);
    int*   esrc    = (int*)alloc((size_t)E * 4);
    short* h2 = h1;   // alias: h1 dead after GEMM2, h2 written by agg2

    // graph prep
    k_zero <<<(N + 255) / 256, 256, 0, stream>>>(deg_out, deg_in, cursor, N);
    k_count<<<(E + 255) / 256, 256, 0, stream>>>(src, dst, deg_out, deg_in, E);
    k_inv  <<<(N + 255) / 256, 256, 0, stream>>>(deg_out, deg_in, inv_out, inv_in, N);
    k_scan <<<1, 1024, 0, stream>>>(deg_in, row_off);
    k_fill <<<(E + 255) / 256, 256, 0, stream>>>(src, dst, row_off, cursor, esrc, E);
    k_rowsum<<<N, 64, 0, stream>>>(row_off, esrc, inv_out, inv_in, rowsum);

    // operand conversion
    k_cvt_scale<<<(N * IN / 4 + 255) / 256, 256, 0, stream>>>(features, inv_out, featb,
                                                              N * IN / 4, IN / 4);
    k_tr3<<<dim3(H / 64, IN / 64), 256, 0, stream>>>(W1, W1t, IN, H);
    k_tr3<<<dim3(N / 64, H / 64), 256, 0, stream>>>(W2, W2t, H, N);

    // conv1: aggregate features first (F=512), then GEMM1 with rowsum*b1 epilogue
    agg_strip<0><<<dim3(1, N), 64, 0, stream>>>(featb, aggF, row_off, esrc, inv_in, IN);
    gemm8p<1><<<dim3(H / 256, N / 256), 512, 0, stream>>>(aggF, W1t, h1, b1, rowsum, N, H, IN);

    // conv2: project first, then aggregate (L2-striped: stripe = bid%8 = XCD)
    gemm8p<2><<<dim3(N / 256, N / 256), 512, 0, stream>>>(h1, W2t, x2s, nullptr, inv_out, N, N, H);
    agg_strip<1><<<dim3(N / 512, N), 64, 0, stream>>>(x2s, h2, row_off, esrc, inv_in, N);

    // head: split-K MFMA GEMM -> partials -> reduce+softmax
    k_headgemm<<<dim3(N / 256, 8), 256, 0, stream>>>(h2, Wl, logitsP);
    k_soft<<<N / 64, 64, 0, stream>>>(logitsP, bl, out);
}